// Round 17
// baseline (223.443 us; speedup 1.0000x reference)
//
#include <hip/hip_runtime.h>
#include <math.h>

#define NN 20000
#define NE 320000
#define F 128
#define NLAYER 3
#define MPAD 20032          // 313 * 64
#define MROWS 20096         // 157 * 128 (128-row-tile pad)
#define SCAN_NB 79          // ceil(NN/256)

typedef unsigned int u32;
typedef unsigned short u16;
typedef __attribute__((ext_vector_type(8))) short bf16x8;
typedef __attribute__((ext_vector_type(4))) float f32x4;

__device__ __forceinline__ u16 f2bf(float f) {
    union { float f; u32 u; } x{f};
    u32 r = x.u + 0x7FFFu + ((x.u >> 16) & 1u);
    return (u16)(r >> 16);
}
__device__ __forceinline__ float bflo(u32 u) { return __uint_as_float(u << 16); }
__device__ __forceinline__ float bfhi(u32 u) { return __uint_as_float(u & 0xFFFF0000u); }

__device__ __forceinline__ void gload16(const u16* g, u16* l) {
    __builtin_amdgcn_global_load_lds(
        (const __attribute__((address_space(1))) void*)g,
        (__attribute__((address_space(3))) void*)l, 16, 0, 0);
}

// ---------------- graph-structure kernels ----------------

__global__ void hist_kernel(const int* __restrict__ dst, int* __restrict__ cnt, int e) {
    int i = blockIdx.x * blockDim.x + threadIdx.x;
    if (i < e) atomicAdd(&cnt[dst[i]], 1);
}

__global__ void scan_p1(const int* __restrict__ cnt, int* __restrict__ bsum) {
    __shared__ int sh[256];
    int i = blockIdx.x * 256 + threadIdx.x;
    int t = threadIdx.x;
    sh[t] = (i < NN) ? cnt[i] : 0;
    __syncthreads();
#pragma unroll
    for (int d = 128; d > 0; d >>= 1) {
        if (t < d) sh[t] += sh[t + d];
        __syncthreads();
    }
    if (t == 0) bsum[blockIdx.x] = sh[0];
}

// merged p2+p3: every block scans the 79 block sums redundantly in LDS
__global__ void scan_p23(const int* __restrict__ cnt, const int* __restrict__ bsum,
                         int* __restrict__ off, float* __restrict__ amp,
                         float* __restrict__ att, float avg_log) {
    __shared__ int sh[256];
    __shared__ int sb[128];
    int i = blockIdx.x * 256 + threadIdx.x;
    int t = threadIdx.x;
    if (t < 128) sb[t] = (t < SCAN_NB) ? bsum[t] : 0;
    __syncthreads();
#pragma unroll
    for (int d = 1; d < 128; d <<= 1) {
        int x = (t >= d && t < 128) ? sb[t - d] : 0;
        __syncthreads();
        if (t < 128) sb[t] += x;
        __syncthreads();
    }
    int base = (blockIdx.x == 0) ? 0 : sb[blockIdx.x - 1];
    int v = (i < NN) ? cnt[i] : 0;
    sh[t] = v;
    __syncthreads();
#pragma unroll
    for (int d = 1; d < 256; d <<= 1) {
        int x = (t >= d) ? sh[t - d] : 0;
        __syncthreads();
        sh[t] += x;
        __syncthreads();
    }
    if (i < NN) {
        int incl = sh[t] + base;
        off[i] = incl - v;
        if (i == NN - 1) off[NN] = incl;
        float deg = fmaxf((float)v, 1.0f);
        float ld = logf(deg + 1.0f);
        amp[i] = ld / avg_log;
        att[i] = avg_log / ld;
    }
}

__global__ void scatter_kernel(const int* __restrict__ src, const int* __restrict__ dst,
                               const int* __restrict__ off, int* __restrict__ cur,
                               int* __restrict__ csr, int e) {
    int i = blockIdx.x * blockDim.x + threadIdx.x;
    if (i < e) {
        int d = dst[i];
        int p = atomicAdd(&cur[d], 1);
        csr[off[d] + p] = src[i];
    }
}

// ---------------- combined prep: converts + biases + zero-fills, flat-indexed ----------------

#define P0 640000L                  // xbuf NN*F/4 (float4-vectorized)
#define P1 (P0 + 3L * 256 * 128)    // wpreT
#define P2 (P1 + 3L * 128 * 128)    // wlinT
#define P3 (P2 + 3L * 2048 * 128)   // wpost
#define P4 (P3 + 3L * 256)          // biaspre
#define P5 (P4 + 3L * 128)          // bcomb
#define P6 (P5 + 2L * NN)           // cnt/cur zero
#define P7 (P6 + NN)                // y zero

__global__ void prep_all(const float* __restrict__ x, const float* __restrict__ W_pre,
                         const float* __restrict__ W_lin, const float* __restrict__ W_post,
                         const float* __restrict__ b_pre, const float* __restrict__ b_post,
                         const float* __restrict__ b_lin,
                         u16* __restrict__ xbuf,
                         u16* __restrict__ WpreT, u16* __restrict__ WlinT,
                         u16* __restrict__ Wpostb, float* __restrict__ biaspre,
                         float* __restrict__ bcomb,
                         int* __restrict__ cnt, int* __restrict__ cur,
                         float* __restrict__ y) {
    long i = (long)blockIdx.x * 256 + threadIdx.x;
    if (i < P0) {
        float4 v = *(const float4*)&x[i * 4];
        u16 h[4] = {f2bf(v.x), f2bf(v.y), f2bf(v.z), f2bf(v.w)};
        *(ulong1*)&xbuf[i * 4] = *(ulong1*)h;
    } else if (i < P1) {
        long j = i - P0;
        int l = j / 32768, t = j % 32768;
        int c = t >> 7, k = t & 127;
        int si = (c < 128) ? (k * 128 + c) : ((k + 128) * 128 + (c - 128));
        WpreT[l * 32768 + t] = f2bf(W_pre[l * 32768 + si]);
    } else if (i < P2) {
        long j = i - P1;
        int l = j / 16384, t = j % 16384;
        int c = t >> 7, k = t & 127;
        WlinT[l * 16384 + t] = f2bf(W_lin[l * 16384 + k * 128 + c]);
    } else if (i < P3) {
        long j = i - P2;
        Wpostb[j] = f2bf(W_post[j]);
    } else if (i < P4) {
        long j = i - P3;
        int l = j / 256, t = j % 256;
        biaspre[l * 256 + t] = (t < 128) ? b_pre[l * 128 + t] : 0.f;
    } else if (i < P5) {
        long j = i - P4;
        int l = j / 128, t = j % 128;
        float s = b_lin[l * 128 + t];
        for (int c = 0; c < 128; ++c) s += b_post[l * 128 + c] * W_lin[l * 16384 + c * 128 + t];
        bcomb[l * 128 + t] = s;
    } else if (i < P6) {
        long j = i - P5;
        if (j < NN) cnt[j] = 0; else cur[j - NN] = 0;
    } else if (i < P7) {
        y[i - P6] = 0.f;
    }
}

// ---------------- aggregation: persistent grid, one WAVE per node, 16-wide batches ----------------

#define PROC(u) { float v_; \
    v_ = bflo(u); s0 += v_; q0 = fmaf(v_, v_, q0); mn0 = fminf(mn0, v_); mx0 = fmaxf(mx0, v_); \
    v_ = bfhi(u); s1 += v_; q1 = fmaf(v_, v_, q1); mn1 = fminf(mn1, v_); mx1 = fmaxf(mx1, v_); }

__global__ __launch_bounds__(256) void agg_kernel(
    const u16* __restrict__ preC, const u16* __restrict__ preB,
    const int* __restrict__ off, const int* __restrict__ csr,
    u16* __restrict__ aggb) {
    int tid = threadIdx.x, w = tid >> 6, lane = tid & 63;
    const u32* bpl = (const u32*)preB + lane;          // row stride 64 u32
    int nwaves = gridDim.x * 4;
    for (int node = blockIdx.x * 4 + w; node < NN; node += nwaves) {
        int o0 = off[node], o1 = off[node + 1];
        int deg = o1 - o0;
        float s0 = 0, s1 = 0, q0 = 0, q1 = 0;
        float mn0 = 1e30f, mn1 = 1e30f, mx0 = -1e30f, mx1 = -1e30f;
        int j = o0;
        int nb = deg >> 4;
        if (nb > 0) {
            int idx[16];
#pragma unroll
            for (int p = 0; p < 16; ++p) idx[p] = csr[j + p];
            for (int b = 1; b < nb; ++b) {
                u32 u[16];
#pragma unroll
                for (int p = 0; p < 16; ++p) u[p] = bpl[(size_t)idx[p] * 64];
#pragma unroll
                for (int p = 0; p < 16; ++p) idx[p] = csr[j + 16 * b + p];
#pragma unroll
                for (int p = 0; p < 16; ++p) PROC(u[p]);
            }
            {
                u32 u[16];
#pragma unroll
                for (int p = 0; p < 16; ++p) u[p] = bpl[(size_t)idx[p] * 64];
#pragma unroll
                for (int p = 0; p < 16; ++p) PROC(u[p]);
            }
            j += nb * 16;
        }
        if (j + 8 <= o1) {
            u32 u[8];
            int idx[8];
#pragma unroll
            for (int p = 0; p < 8; ++p) idx[p] = csr[j + p];
#pragma unroll
            for (int p = 0; p < 8; ++p) u[p] = bpl[(size_t)idx[p] * 64];
#pragma unroll
            for (int p = 0; p < 8; ++p) PROC(u[p]);
            j += 8;
        }
        if (j + 4 <= o1) {
            int i0 = csr[j], i1 = csr[j + 1], i2 = csr[j + 2], i3 = csr[j + 3];
            u32 u0 = bpl[(size_t)i0 * 64];
            u32 u1 = bpl[(size_t)i1 * 64];
            u32 u2 = bpl[(size_t)i2 * 64];
            u32 u3 = bpl[(size_t)i3 * 64];
            PROC(u0); PROC(u1); PROC(u2); PROC(u3);
            j += 4;
        }
        for (; j < o1; ++j) { u32 u = bpl[(size_t)csr[j] * 64]; PROC(u); }

        float mean0, mean1, sum0, sum1, std0, std1, lo0, lo1, hi0, hi1;
        if (deg == 0) {
            sum0 = sum1 = 0.f; mean0 = mean1 = 0.f;
            std0 = std1 = sqrtf(1e-5f);
            lo0 = lo1 = hi0 = hi1 = 0.f;
        } else {
            u32 uc = ((const u32*)preC)[(size_t)node * 64 + lane];
            float c0 = bflo(uc), c1 = bfhi(uc), dg = (float)deg;
            sum0 = dg * c0 + s0; mean0 = sum0 / dg;
            sum1 = dg * c1 + s1; mean1 = sum1 / dg;
            float msq0 = c0 * c0 + (2.f * c0 * s0 + q0) / dg;
            float msq1 = c1 * c1 + (2.f * c1 * s1 + q1) / dg;
            std0 = sqrtf(fmaxf(msq0 - mean0 * mean0, 0.f) + 1e-5f);
            std1 = sqrtf(fmaxf(msq1 - mean1 * mean1, 0.f) + 1e-5f);
            lo0 = c0 + mn0; lo1 = c1 + mn1; hi0 = c0 + mx0; hi1 = c1 + mx1;
        }
        u32* cr = (u32*)aggb + (size_t)node * 320 + lane;    // row = 640 bf16
        float f0[5] = {mean0, sum0, std0, lo0, hi0};
        float f1[5] = {mean1, sum1, std1, lo1, hi1};
#pragma unroll
        for (int a = 0; a < 5; ++a)
            cr[a * 64] = (u32)f2bf(f0[a]) | ((u32)f2bf(f1[a]) << 16);
    }
}

// ---------------- wprod GEMM (BtK build, tiny) ----------------

__global__ __launch_bounds__(256) void mfma_gemm(
    const u16* __restrict__ A, int lda,
    const u16* __restrict__ Bt, int K,
    u16* __restrict__ C, int Mreal,
    size_t aS, size_t bS, size_t cS) {
    __shared__ u16 As[64 * 32];
    __shared__ u16 Bs[128 * 32];
    int row0 = blockIdx.x * 64, col0 = blockIdx.y * 128;
    int z = blockIdx.z;
    A += (size_t)z * aS; Bt += (size_t)z * bS; C += (size_t)z * cS;
    int tid = threadIdx.x;
    int w = tid >> 6, lane = tid & 63;

    int arow = tid >> 2, asl = tid & 3;
    const u16* agp = A + (size_t)(row0 + arow) * lda + ((asl ^ ((arow >> 1) & 3)) << 3);
    u16* alds = As + w * 512;
    int br0 = tid >> 2;
    int br1 = 64 + (tid >> 2);
    const u16* bgp0 = Bt + (size_t)(col0 + br0) * K + (((tid & 3) ^ ((br0 >> 1) & 3)) << 3);
    const u16* bgp1 = Bt + (size_t)(col0 + br1) * K + (((tid & 3) ^ ((br1 >> 1) & 3)) << 3);
    u16* blds0 = Bs + w * 512;
    u16* blds1 = Bs + 2048 + w * 512;

    f32x4 acc[2][4];
#pragma unroll
    for (int m = 0; m < 2; ++m)
#pragma unroll
        for (int n = 0; n < 4; ++n) acc[m][n] = (f32x4){0.f, 0.f, 0.f, 0.f};

    int s = lane >> 4, r = lane & 15;
    int wr = (w >> 1) * 32, wc = (w & 1) * 64;

    for (int k0 = 0; k0 < K; k0 += 32) {
        gload16(agp + k0, alds);
        gload16(bgp0 + k0, blds0);
        gload16(bgp1 + k0, blds1);
        __syncthreads();
        bf16x8 a[2], b[4];
#pragma unroll
        for (int m = 0; m < 2; ++m) {
            int row = wr + m * 16 + r;
            a[m] = *(const bf16x8*)&As[row * 32 + ((s ^ ((row >> 1) & 3)) << 3)];
        }
#pragma unroll
        for (int n = 0; n < 4; ++n) {
            int col = wc + n * 16 + r;
            b[n] = *(const bf16x8*)&Bs[col * 32 + ((s ^ ((col >> 1) & 3)) << 3)];
        }
#pragma unroll
        for (int m = 0; m < 2; ++m)
#pragma unroll
            for (int n = 0; n < 4; ++n)
                acc[m][n] = __builtin_amdgcn_mfma_f32_16x16x32_bf16(a[m], b[n], acc[m][n], 0, 0, 0);
        __syncthreads();
    }

#pragma unroll
    for (int m = 0; m < 2; ++m) {
#pragma unroll
        for (int n = 0; n < 4; ++n) {
            int gcol = col0 + wc + n * 16 + r;
#pragma unroll
            for (int j = 0; j < 4; ++j) {
                int grow = row0 + wr + m * 16 + s * 4 + j;
                if (grow < Mreal) {
                    u16 h = f2bf(acc[m][n][j]);
                    size_t idx;
                    if (gcol < 128) idx = (size_t)grow * 768 + gcol;
                    else {
                        int t2 = gcol - 128;
                        int gg = t2 / 640;
                        int ko = 128 + t2 - gg * 640;
                        idx = (size_t)(gg * 128 + grow) * 768 + ko;
                    }
                    C[idx] = h;
                }
            }
        }
    }
}

// ---------------- pre2: 128-row tile, depth-2 counted-vmcnt pre GEMM ----------------

__global__ __launch_bounds__(256) void pre2(
    const u16* __restrict__ xin,        // [MROWS][128]
    const u16* __restrict__ Wp,         // WpreT layer base [256][128]
    const float* __restrict__ biasl,    // biaspre layer base [256]
    u16* __restrict__ preC, u16* __restrict__ preB) {
    __shared__ u16 S[3][8192];
    int g = blockIdx.x;
    int row = (g >> 4) * 8 + (g & 7);
    if (row >= 157) return;
    int row0 = row * 128;
    int cb = (g >> 3) & 1;
    int tid = threadIdx.x;
    int w = tid >> 6, lane = tid & 63;
    int r = lane & 15, s4 = lane >> 4;
    int wr = (w >> 1) * 64, wcb = (w & 1) * 64;

    const u16* gp[4];
#pragma unroll
    for (int p = 0; p < 4; ++p) {
        int lid = tid + 256 * p;
        int rt = lid >> 2, q = lid & 3;
        int koff = (q ^ ((rt >> 1) & 3)) << 3;
        if (rt < 128) gp[p] = xin + (size_t)(row0 + rt) * 128 + koff;
        else          gp[p] = Wp + (size_t)(cb * 128 + (rt - 128)) * 128 + koff;
    }

    f32x4 acc[4][4];
#pragma unroll
    for (int m = 0; m < 4; ++m)
#pragma unroll
        for (int n = 0; n < 4; ++n) acc[m][n] = (f32x4){0.f, 0.f, 0.f, 0.f};

    auto STAGE = [&](int t, int b) {
#pragma unroll
        for (int p = 0; p < 4; ++p)
            gload16(gp[p] + t * 32, &S[b][(size_t)(tid + 256 * p) * 8]);
    };

    STAGE(0, 0);
    STAGE(1, 1);
    asm volatile("s_waitcnt vmcnt(4)" ::: "memory");
    __builtin_amdgcn_s_barrier();
    asm volatile("" ::: "memory");

    for (int t = 0; t < 4; ++t) {
        if (t + 2 < 4) STAGE(t + 2, (t + 2) % 3);
        const u16* Sb = S[t % 3];
        bf16x8 a[4], b[4];
#pragma unroll
        for (int m = 0; m < 4; ++m) {
            int rw = wr + m * 16 + r;
            a[m] = *(const bf16x8*)&Sb[rw * 32 + ((s4 ^ ((rw >> 1) & 3)) << 3)];
        }
#pragma unroll
        for (int n = 0; n < 4; ++n) {
            int cB = wcb + n * 16 + r;
            b[n] = *(const bf16x8*)&Sb[4096 + cB * 32 + ((s4 ^ ((cB >> 1) & 3)) << 3)];
        }
#pragma unroll
        for (int m = 0; m < 4; ++m)
#pragma unroll
            for (int n = 0; n < 4; ++n)
                acc[m][n] = __builtin_amdgcn_mfma_f32_16x16x32_bf16(a[m], b[n], acc[m][n], 0, 0, 0);
        if (t < 3) {
            if (t + 2 < 4) asm volatile("s_waitcnt vmcnt(4)" ::: "memory");
            else           asm volatile("s_waitcnt vmcnt(0)" ::: "memory");
            __builtin_amdgcn_s_barrier();
            asm volatile("" ::: "memory");
        }
    }

    u16* out = cb ? preB : preC;
    const float* bs = biasl + cb * 128;
#pragma unroll
    for (int m = 0; m < 4; ++m)
#pragma unroll
        for (int n = 0; n < 4; ++n) {
            int gcol = wcb + n * 16 + r;
            float bv = bs[gcol];
#pragma unroll
            for (int j = 0; j < 4; ++j) {
                int grow = row0 + wr + m * 16 + s4 * 4 + j;
                out[(size_t)grow * 128 + gcol] = f2bf(acc[m][n][j] + bv);
            }
        }
}

// ---------------- comb2: 128-row tile, depth-2 counted-vmcnt comb GEMM ----------------

template <bool OUT>
__global__ __launch_bounds__(256) void comb2(
    const u16* __restrict__ xin,        // [MROWS][128]
    const u16* __restrict__ aggb,       // [MROWS][640]
    const u16* __restrict__ BtK,        // [384][768], row = g*128 + outcol
    const float* __restrict__ bias,     // bcomb 128
    const float* __restrict__ amp, const float* __restrict__ att,
    u16* __restrict__ xout,             // [MROWS][128]  (!OUT)
    const float* __restrict__ Wout,     // [128]         (OUT)
    const float* __restrict__ bout,     // [1]           (OUT)
    float* __restrict__ y) {            // [NN]          (OUT)
    __shared__ u16 S[3][10240];         // 3 x 20 KB: A 128x32 @0, B 192x32 @4096 (u16)
    int g = blockIdx.x;
    int row = (g >> 4) * 8 + (g & 7);
    if (row >= 157) return;
    int row0 = row * 128;
    int cb = (g >> 3) & 1;              // 64-col half
    int tid = threadIdx.x;
    int w = tid >> 6, lane = tid & 63;
    int r = lane & 15, s4 = lane >> 4;
    int wr = (w >> 1) * 64, wc = (w & 1) * 32;

    int rtA0 = tid >> 2, qA = tid & 3;
    int rtA1 = rtA0 + 64;
    int koffA0 = (qA ^ ((rtA0 >> 1) & 3)) << 3;
    int koffA1 = (qA ^ ((rtA1 >> 1) & 3)) << 3;
    const u16* xA0 = xin + (size_t)(row0 + rtA0) * 128 + koffA0;
    const u16* xA1 = xin + (size_t)(row0 + rtA1) * 128 + koffA1;
    const u16* gA0 = aggb + (size_t)(row0 + rtA0) * 640 + koffA0 - 128;
    const u16* gA1 = aggb + (size_t)(row0 + rtA1) * 640 + koffA1 - 128;
    const u16* bB[3];
#pragma unroll
    for (int p = 2; p < 5; ++p) {
        int lid = tid + 256 * p;
        int rt = lid >> 2, q = lid & 3;
        int rb = rt - 128, gg = rb >> 6, jj = rb & 63;
        int koff = (q ^ ((rt >> 1) & 3)) << 3;
        bB[p - 2] = BtK + (size_t)(gg * 128 + cb * 64 + jj) * 768 + koff;
    }

    f32x4 acc[4][3][2];
#pragma unroll
    for (int m = 0; m < 4; ++m)
#pragma unroll
        for (int gg = 0; gg < 3; ++gg)
#pragma unroll
            for (int n = 0; n < 2; ++n) acc[m][gg][n] = (f32x4){0.f, 0.f, 0.f, 0.f};

    auto STAGE = [&](int t, int b) {
        const u16* a0 = (t < 4) ? (xA0 + t * 32) : (gA0 + t * 32);
        const u16* a1 = (t < 4) ? (xA1 + t * 32) : (gA1 + t * 32);
        gload16(a0, &S[b][(size_t)tid * 8]);
        gload16(a1, &S[b][(size_t)(tid + 256) * 8]);
#pragma unroll
        for (int p = 2; p < 5; ++p)
            gload16(bB[p - 2] + t * 32, &S[b][(size_t)(tid + 256 * p) * 8]);
    };

    STAGE(0, 0);
    STAGE(1, 1);
    asm volatile("s_waitcnt vmcnt(5)" ::: "memory");
    __builtin_amdgcn_s_barrier();
    asm volatile("" ::: "memory");

    int buf = 0;
    for (int t = 0; t < 24; ++t) {
        if (t + 2 < 24) STAGE(t + 2, (t + 2) % 3);
        const u16* Sb = S[buf];
        bf16x8 a[4];
#pragma unroll
        for (int m = 0; m < 4; ++m) {
            int rw = wr + m * 16 + r;
            a[m] = *(const bf16x8*)&Sb[rw * 32 + ((s4 ^ ((rw >> 1) & 3)) << 3)];
        }
#pragma unroll
        for (int gg = 0; gg < 3; ++gg) {
            if (gg > 0 && t < 4) continue;       // zero B-block for k<128
#pragma unroll
            for (int n = 0; n < 2; ++n) {
                int rb = gg * 64 + wc + n * 16 + r;
                bf16x8 b = *(const bf16x8*)&Sb[4096 + rb * 32 + ((s4 ^ ((rb >> 1) & 3)) << 3)];
#pragma unroll
                for (int m = 0; m < 4; ++m)
                    acc[m][gg][n] = __builtin_amdgcn_mfma_f32_16x16x32_bf16(a[m], b, acc[m][gg][n], 0, 0, 0);
            }
        }
        if (t < 23) {
            if (t + 2 < 24) asm volatile("s_waitcnt vmcnt(5)" ::: "memory");
            else            asm volatile("s_waitcnt vmcnt(0)" ::: "memory");
            __builtin_amdgcn_s_barrier();
            asm volatile("" ::: "memory");
        }
        buf = (buf == 2) ? 0 : buf + 1;
    }

    int gcb = cb * 64 + wc;
#pragma unroll
    for (int m = 0; m < 4; ++m)
#pragma unroll
        for (int j = 0; j < 4; ++j) {
            int grow = row0 + wr + m * 16 + s4 * 4 + j;
            if (grow >= NN) continue;
            float av = amp[grow], tv = att[grow];
            if (OUT) {
                float ps = 0.f;
#pragma unroll
                for (int n = 0; n < 2; ++n) {
                    int gcol = gcb + n * 16 + r;
                    float v = acc[m][0][n][j] + av * acc[m][1][n][j] + tv * acc[m][2][n][j] + bias[gcol];
                    v = fmaxf(v, 0.f);
                    ps = fmaf(v, Wout[gcol], ps);
                }
                ps += __shfl_xor(ps, 1, 16);
                ps += __shfl_xor(ps, 2, 16);
                ps += __shfl_xor(ps, 4, 16);
                ps += __shfl_xor(ps, 8, 16);
                if (r == 0) {
                    if (cb == 0 && wc == 0) ps += bout[0];
                    atomicAdd(&y[grow], ps);
                }
            } else {
#pragma unroll
                for (int n = 0; n < 2; ++n) {
                    int gcol = gcb + n * 16 + r;
                    float v = acc[m][0][n][j] + av * acc[m][1][n][j] + tv * acc[m][2][n][j] + bias[gcol];
                    v = fmaxf(v, 0.f);
                    xout[(size_t)grow * F + gcol] = f2bf(v);
                }
            }
        }
}

// ---------------- host ----------------

extern "C" void kernel_launch(void* const* d_in, const int* in_sizes, int n_in,
                              void* d_out, int out_size, void* d_ws, size_t ws_size,
                              hipStream_t stream) {
    const float* x_in   = (const float*)d_in[0];
    const int*   ei     = (const int*)d_in[1];
    const float* W_pre  = (const float*)d_in[2];
    const float* b_pre  = (const float*)d_in[3];
    const float* W_post = (const float*)d_in[4];
    const float* b_post = (const float*)d_in[5];
    const float* W_lin  = (const float*)d_in[6];
    const float* b_lin  = (const float*)d_in[7];
    const float* W_out  = (const float*)d_in[8];
    const float* b_out  = (const float*)d_in[9];

    const int* src = ei;
    const int* dst = ei + NE;

    double sl = 0.0;
    for (int i = 0; i < 33; ++i) sl += log((double)(i + 1));
    float avg_log = (float)(sl / 33.0);

    char* ws = (char*)d_ws;
    size_t p = 0;
    auto alloc = [&](size_t bytes) { void* r = ws + p; p += (bytes + 255) & ~(size_t)255; return r; };
    u16*   xbufA   = (u16*)alloc((size_t)MROWS * F * 2);
    u16*   xbufB   = (u16*)alloc((size_t)MROWS * F * 2);
    u16*   aggb    = (u16*)alloc((size_t)MROWS * 640 * 2);
    u16*   preC    = (u16*)alloc((size_t)MROWS * F * 2);
    u16*   preB    = (u16*)alloc((size_t)MROWS * F * 2);
    u16*   WpreT   = (u16*)alloc((size_t)3 * 256 * 128 * 2);
    u16*   Wpostb  = (u16*)alloc((size_t)3 * 2048 * 128 * 2);
    u16*   WlinT   = (u16*)alloc((size_t)3 * 128 * 128 * 2);
    u16*   BtK     = (u16*)alloc((size_t)3 * 384 * 768 * 2);
    float* biaspre = (float*)alloc((size_t)3 * 256 * 4);
    float* bcomb   = (float*)alloc((size_t)3 * 128 * 4);
    float* amp     = (float*)alloc((size_t)MPAD * 4);
    float* att     = (float*)alloc((size_t)MPAD * 4);
    int*   cnt     = (int*)alloc((size_t)NN * 4);
    int*   offs    = (int*)alloc((size_t)(NN + 1) * 4);
    int*   cur     = (int*)alloc((size_t)NN * 4);
    int*   csr     = (int*)alloc((size_t)NE * 4);
    int*   bsum    = (int*)alloc((size_t)SCAN_NB * 4);
    (void)ws_size;

    float* y = (float*)d_out;

    prep_all<<<(int)((P7 + 255) / 256), 256, 0, stream>>>(
        x_in, W_pre, W_lin, W_post, b_pre, b_post, b_lin,
        xbufA, WpreT, WlinT, Wpostb, biaspre, bcomb, cnt, cur, y);

    hist_kernel<<<(NE + 255) / 256, 256, 0, stream>>>(dst, cnt, NE);
    scan_p1<<<SCAN_NB, 256, 0, stream>>>(cnt, bsum);
    scan_p23<<<SCAN_NB, 256, 0, stream>>>(cnt, bsum, offs, amp, att, avg_log);
    scatter_kernel<<<(NE + 255) / 256, 256, 0, stream>>>(src, dst, offs, cur, csr, NE);

    // BtK[l] = (W_post@W_lin)^T scattered into [384][768] layout, all 3 layers
    mfma_gemm<<<dim3(2, 16, 3), 256, 0, stream>>>(
        WlinT, 128, Wpostb, 128, BtK, 128,
        16384, 262144, 294912);

    // layer-0 pre: preC/preB = x @ [Wtop|Wbot] + [b_pre|0]
    pre2<<<320, 256, 0, stream>>>(xbufA, WpreT, biaspre, preC, preB);

    u16* xc = xbufA;
    u16* xn = xbufB;
    for (int l = 0; l < NLAYER; ++l) {
        agg_kernel<<<2048, 256, 0, stream>>>(preC, preB, offs, csr, aggb);
        if (l < NLAYER - 1) {
            comb2<false><<<320, 256, 0, stream>>>(
                xc, aggb, BtK + (size_t)l * 294912, bcomb + (size_t)l * 128,
                amp, att, xn, nullptr, nullptr, nullptr);
            pre2<<<320, 256, 0, stream>>>(
                xn, WpreT + (size_t)(l + 1) * 32768, biaspre + (size_t)(l + 1) * 256,
                preC, preB);
            u16* tmp = xc; xc = xn; xn = tmp;
        } else {
            comb2<true><<<320, 256, 0, stream>>>(
                xc, aggb, BtK + (size_t)l * 294912, bcomb + (size_t)l * 128,
                amp, att, nullptr, W_out, b_out, y);
        }
    }
}

// Round 18
// 211.266 us; speedup vs baseline: 1.0576x; 1.0576x over previous
//
#include <hip/hip_runtime.h>
#include <math.h>

#define NN 20000
#define NE 320000
#define F 128
#define NLAYER 3
#define MPAD 20032          // 313 * 64
#define MROWS 20096         // 157 * 128 (128-row-tile pad)
#define SCAN_NB 79          // ceil(NN/256)

typedef unsigned int u32;
typedef unsigned short u16;
typedef __attribute__((ext_vector_type(8))) short bf16x8;
typedef __attribute__((ext_vector_type(4))) float f32x4;

__device__ __forceinline__ u16 f2bf(float f) {
    union { float f; u32 u; } x{f};
    u32 r = x.u + 0x7FFFu + ((x.u >> 16) & 1u);
    return (u16)(r >> 16);
}
__device__ __forceinline__ float bflo(u32 u) { return __uint_as_float(u << 16); }
__device__ __forceinline__ float bfhi(u32 u) { return __uint_as_float(u & 0xFFFF0000u); }

__device__ __forceinline__ void gload16(const u16* g, u16* l) {
    __builtin_amdgcn_global_load_lds(
        (const __attribute__((address_space(1))) void*)g,
        (__attribute__((address_space(3))) void*)l, 16, 0, 0);
}

// ---------------- graph-structure kernels ----------------

__global__ void hist_kernel(const int* __restrict__ dst, int* __restrict__ cnt, int e) {
    int i = blockIdx.x * blockDim.x + threadIdx.x;
    if (i < e) atomicAdd(&cnt[dst[i]], 1);
}

__global__ void scan_p1(const int* __restrict__ cnt, int* __restrict__ bsum) {
    __shared__ int sh[256];
    int i = blockIdx.x * 256 + threadIdx.x;
    int t = threadIdx.x;
    sh[t] = (i < NN) ? cnt[i] : 0;
    __syncthreads();
#pragma unroll
    for (int d = 128; d > 0; d >>= 1) {
        if (t < d) sh[t] += sh[t + d];
        __syncthreads();
    }
    if (t == 0) bsum[blockIdx.x] = sh[0];
}

// merged p2+p3: every block scans the 79 block sums redundantly in LDS
__global__ void scan_p23(const int* __restrict__ cnt, const int* __restrict__ bsum,
                         int* __restrict__ off, float* __restrict__ amp,
                         float* __restrict__ att, float avg_log) {
    __shared__ int sh[256];
    __shared__ int sb[128];
    int i = blockIdx.x * 256 + threadIdx.x;
    int t = threadIdx.x;
    if (t < 128) sb[t] = (t < SCAN_NB) ? bsum[t] : 0;
    __syncthreads();
#pragma unroll
    for (int d = 1; d < 128; d <<= 1) {
        int x = (t >= d && t < 128) ? sb[t - d] : 0;
        __syncthreads();
        if (t < 128) sb[t] += x;
        __syncthreads();
    }
    int base = (blockIdx.x == 0) ? 0 : sb[blockIdx.x - 1];
    int v = (i < NN) ? cnt[i] : 0;
    sh[t] = v;
    __syncthreads();
#pragma unroll
    for (int d = 1; d < 256; d <<= 1) {
        int x = (t >= d) ? sh[t - d] : 0;
        __syncthreads();
        sh[t] += x;
        __syncthreads();
    }
    if (i < NN) {
        int incl = sh[t] + base;
        off[i] = incl - v;
        if (i == NN - 1) off[NN] = incl;
        float deg = fmaxf((float)v, 1.0f);
        float ld = logf(deg + 1.0f);
        amp[i] = ld / avg_log;
        att[i] = avg_log / ld;
    }
}

__global__ void scatter_kernel(const int* __restrict__ src, const int* __restrict__ dst,
                               const int* __restrict__ off, int* __restrict__ cur,
                               int* __restrict__ csr, int e) {
    int i = blockIdx.x * blockDim.x + threadIdx.x;
    if (i < e) {
        int d = dst[i];
        int p = atomicAdd(&cur[d], 1);
        csr[off[d] + p] = src[i];
    }
}

// ---------------- combined prep: converts + biases + zero-fills, flat-indexed ----------------

#define P0 640000L                  // xbuf NN*F/4 (float4-vectorized)
#define P1 (P0 + 3L * 256 * 128)    // wpreT
#define P2 (P1 + 3L * 128 * 128)    // wlinT
#define P3 (P2 + 3L * 2048 * 128)   // wpost
#define P4 (P3 + 3L * 256)          // biaspre
#define P5 (P4 + 3L * 128)          // bcomb
#define P6 (P5 + 2L * NN)           // cnt/cur zero
#define P7 (P6 + NN)                // y zero

__global__ void prep_all(const float* __restrict__ x, const float* __restrict__ W_pre,
                         const float* __restrict__ W_lin, const float* __restrict__ W_post,
                         const float* __restrict__ b_pre, const float* __restrict__ b_post,
                         const float* __restrict__ b_lin,
                         u16* __restrict__ xbuf,
                         u16* __restrict__ WpreT, u16* __restrict__ WlinT,
                         u16* __restrict__ Wpostb, float* __restrict__ biaspre,
                         float* __restrict__ bcomb,
                         int* __restrict__ cnt, int* __restrict__ cur,
                         float* __restrict__ y) {
    long i = (long)blockIdx.x * 256 + threadIdx.x;
    if (i < P0) {
        float4 v = *(const float4*)&x[i * 4];
        u16 h[4] = {f2bf(v.x), f2bf(v.y), f2bf(v.z), f2bf(v.w)};
        *(ulong1*)&xbuf[i * 4] = *(ulong1*)h;
    } else if (i < P1) {
        long j = i - P0;
        int l = j / 32768, t = j % 32768;
        int c = t >> 7, k = t & 127;
        int si = (c < 128) ? (k * 128 + c) : ((k + 128) * 128 + (c - 128));
        WpreT[l * 32768 + t] = f2bf(W_pre[l * 32768 + si]);
    } else if (i < P2) {
        long j = i - P1;
        int l = j / 16384, t = j % 16384;
        int c = t >> 7, k = t & 127;
        WlinT[l * 16384 + t] = f2bf(W_lin[l * 16384 + k * 128 + c]);
    } else if (i < P3) {
        long j = i - P2;
        Wpostb[j] = f2bf(W_post[j]);
    } else if (i < P4) {
        long j = i - P3;
        int l = j / 256, t = j % 256;
        biaspre[l * 256 + t] = (t < 128) ? b_pre[l * 128 + t] : 0.f;
    } else if (i < P5) {
        long j = i - P4;
        int l = j / 128, t = j % 128;
        float s = b_lin[l * 128 + t];
        for (int c = 0; c < 128; ++c) s += b_post[l * 128 + c] * W_lin[l * 16384 + c * 128 + t];
        bcomb[l * 128 + t] = s;
    } else if (i < P6) {
        long j = i - P5;
        if (j < NN) cnt[j] = 0; else cur[j - NN] = 0;
    } else if (i < P7) {
        y[i - P6] = 0.f;
    }
}

// ---------------- aggregation: persistent grid, one WAVE per node ----------------
// software-pipelined: next batch's 8 index loads issued while current gathers in flight

#define PROC(u) { float v_; \
    v_ = bflo(u); s0 += v_; q0 = fmaf(v_, v_, q0); mn0 = fminf(mn0, v_); mx0 = fmaxf(mx0, v_); \
    v_ = bfhi(u); s1 += v_; q1 = fmaf(v_, v_, q1); mn1 = fminf(mn1, v_); mx1 = fmaxf(mx1, v_); }

__global__ __launch_bounds__(256) void agg_kernel(
    const u16* __restrict__ preC, const u16* __restrict__ preB,
    const int* __restrict__ off, const int* __restrict__ csr,
    u16* __restrict__ aggb) {
    int tid = threadIdx.x, w = tid >> 6, lane = tid & 63;
    const u32* bpl = (const u32*)preB + lane;          // row stride 64 u32
    int nwaves = gridDim.x * 4;
    for (int node = blockIdx.x * 4 + w; node < NN; node += nwaves) {
        int o0 = off[node], o1 = off[node + 1];
        int deg = o1 - o0;
        float s0 = 0, s1 = 0, q0 = 0, q1 = 0;
        float mn0 = 1e30f, mn1 = 1e30f, mx0 = -1e30f, mx1 = -1e30f;
        int j = o0;
        int nb = deg >> 3;
        if (nb > 0) {
            int idx[8];
#pragma unroll
            for (int p = 0; p < 8; ++p) idx[p] = csr[j + p];
            for (int b = 1; b < nb; ++b) {
                u32 u[8];
#pragma unroll
                for (int p = 0; p < 8; ++p) u[p] = bpl[(size_t)idx[p] * 64];
#pragma unroll
                for (int p = 0; p < 8; ++p) idx[p] = csr[j + 8 * b + p];
#pragma unroll
                for (int p = 0; p < 8; ++p) PROC(u[p]);
            }
            {
                u32 u[8];
#pragma unroll
                for (int p = 0; p < 8; ++p) u[p] = bpl[(size_t)idx[p] * 64];
#pragma unroll
                for (int p = 0; p < 8; ++p) PROC(u[p]);
            }
            j += nb * 8;
        }
        if (j + 4 <= o1) {
            int i0 = csr[j], i1 = csr[j + 1], i2 = csr[j + 2], i3 = csr[j + 3];
            u32 u0 = bpl[(size_t)i0 * 64];
            u32 u1 = bpl[(size_t)i1 * 64];
            u32 u2 = bpl[(size_t)i2 * 64];
            u32 u3 = bpl[(size_t)i3 * 64];
            PROC(u0); PROC(u1); PROC(u2); PROC(u3);
            j += 4;
        }
        for (; j < o1; ++j) { u32 u = bpl[(size_t)csr[j] * 64]; PROC(u); }

        float mean0, mean1, sum0, sum1, std0, std1, lo0, lo1, hi0, hi1;
        if (deg == 0) {
            sum0 = sum1 = 0.f; mean0 = mean1 = 0.f;
            std0 = std1 = sqrtf(1e-5f);
            lo0 = lo1 = hi0 = hi1 = 0.f;
        } else {
            u32 uc = ((const u32*)preC)[(size_t)node * 64 + lane];
            float c0 = bflo(uc), c1 = bfhi(uc), dg = (float)deg;
            sum0 = dg * c0 + s0; mean0 = sum0 / dg;
            sum1 = dg * c1 + s1; mean1 = sum1 / dg;
            float msq0 = c0 * c0 + (2.f * c0 * s0 + q0) / dg;
            float msq1 = c1 * c1 + (2.f * c1 * s1 + q1) / dg;
            std0 = sqrtf(fmaxf(msq0 - mean0 * mean0, 0.f) + 1e-5f);
            std1 = sqrtf(fmaxf(msq1 - mean1 * mean1, 0.f) + 1e-5f);
            lo0 = c0 + mn0; lo1 = c1 + mn1; hi0 = c0 + mx0; hi1 = c1 + mx1;
        }
        u32* cr = (u32*)aggb + (size_t)node * 320 + lane;    // row = 640 bf16
        float f0[5] = {mean0, sum0, std0, lo0, hi0};
        float f1[5] = {mean1, sum1, std1, lo1, hi1};
#pragma unroll
        for (int a = 0; a < 5; ++a)
            cr[a * 64] = (u32)f2bf(f0[a]) | ((u32)f2bf(f1[a]) << 16);
    }
}

// ---------------- wprod GEMM (BtK build, tiny) ----------------

__global__ __launch_bounds__(256) void mfma_gemm(
    const u16* __restrict__ A, int lda,
    const u16* __restrict__ Bt, int K,
    u16* __restrict__ C, int Mreal,
    size_t aS, size_t bS, size_t cS) {
    __shared__ u16 As[64 * 32];
    __shared__ u16 Bs[128 * 32];
    int row0 = blockIdx.x * 64, col0 = blockIdx.y * 128;
    int z = blockIdx.z;
    A += (size_t)z * aS; Bt += (size_t)z * bS; C += (size_t)z * cS;
    int tid = threadIdx.x;
    int w = tid >> 6, lane = tid & 63;

    int arow = tid >> 2, asl = tid & 3;
    const u16* agp = A + (size_t)(row0 + arow) * lda + ((asl ^ ((arow >> 1) & 3)) << 3);
    u16* alds = As + w * 512;
    int br0 = tid >> 2;
    int br1 = 64 + (tid >> 2);
    const u16* bgp0 = Bt + (size_t)(col0 + br0) * K + (((tid & 3) ^ ((br0 >> 1) & 3)) << 3);
    const u16* bgp1 = Bt + (size_t)(col0 + br1) * K + (((tid & 3) ^ ((br1 >> 1) & 3)) << 3);
    u16* blds0 = Bs + w * 512;
    u16* blds1 = Bs + 2048 + w * 512;

    f32x4 acc[2][4];
#pragma unroll
    for (int m = 0; m < 2; ++m)
#pragma unroll
        for (int n = 0; n < 4; ++n) acc[m][n] = (f32x4){0.f, 0.f, 0.f, 0.f};

    int s = lane >> 4, r = lane & 15;
    int wr = (w >> 1) * 32, wc = (w & 1) * 64;

    for (int k0 = 0; k0 < K; k0 += 32) {
        gload16(agp + k0, alds);
        gload16(bgp0 + k0, blds0);
        gload16(bgp1 + k0, blds1);
        __syncthreads();
        bf16x8 a[2], b[4];
#pragma unroll
        for (int m = 0; m < 2; ++m) {
            int row = wr + m * 16 + r;
            a[m] = *(const bf16x8*)&As[row * 32 + ((s ^ ((row >> 1) & 3)) << 3)];
        }
#pragma unroll
        for (int n = 0; n < 4; ++n) {
            int col = wc + n * 16 + r;
            b[n] = *(const bf16x8*)&Bs[col * 32 + ((s ^ ((col >> 1) & 3)) << 3)];
        }
#pragma unroll
        for (int m = 0; m < 2; ++m)
#pragma unroll
            for (int n = 0; n < 4; ++n)
                acc[m][n] = __builtin_amdgcn_mfma_f32_16x16x32_bf16(a[m], b[n], acc[m][n], 0, 0, 0);
        __syncthreads();
    }

#pragma unroll
    for (int m = 0; m < 2; ++m) {
#pragma unroll
        for (int n = 0; n < 4; ++n) {
            int gcol = col0 + wc + n * 16 + r;
#pragma unroll
            for (int j = 0; j < 4; ++j) {
                int grow = row0 + wr + m * 16 + s * 4 + j;
                if (grow < Mreal) {
                    u16 h = f2bf(acc[m][n][j]);
                    size_t idx;
                    if (gcol < 128) idx = (size_t)grow * 768 + gcol;
                    else {
                        int t2 = gcol - 128;
                        int gg = t2 / 640;
                        int ko = 128 + t2 - gg * 640;
                        idx = (size_t)(gg * 128 + grow) * 768 + ko;
                    }
                    C[idx] = h;
                }
            }
        }
    }
}

// ---------------- pre2: 128-row tile, depth-2 counted-vmcnt pre GEMM ----------------

__global__ __launch_bounds__(256) void pre2(
    const u16* __restrict__ xin,        // [MROWS][128]
    const u16* __restrict__ Wp,         // WpreT layer base [256][128]
    const float* __restrict__ biasl,    // biaspre layer base [256]
    u16* __restrict__ preC, u16* __restrict__ preB) {
    __shared__ u16 S[3][8192];
    int g = blockIdx.x;
    int row = (g >> 4) * 8 + (g & 7);
    if (row >= 157) return;
    int row0 = row * 128;
    int cb = (g >> 3) & 1;
    int tid = threadIdx.x;
    int w = tid >> 6, lane = tid & 63;
    int r = lane & 15, s4 = lane >> 4;
    int wr = (w >> 1) * 64, wcb = (w & 1) * 64;

    const u16* gp[4];
#pragma unroll
    for (int p = 0; p < 4; ++p) {
        int lid = tid + 256 * p;
        int rt = lid >> 2, q = lid & 3;
        int koff = (q ^ ((rt >> 1) & 3)) << 3;
        if (rt < 128) gp[p] = xin + (size_t)(row0 + rt) * 128 + koff;
        else          gp[p] = Wp + (size_t)(cb * 128 + (rt - 128)) * 128 + koff;
    }

    f32x4 acc[4][4];
#pragma unroll
    for (int m = 0; m < 4; ++m)
#pragma unroll
        for (int n = 0; n < 4; ++n) acc[m][n] = (f32x4){0.f, 0.f, 0.f, 0.f};

    auto STAGE = [&](int t, int b) {
#pragma unroll
        for (int p = 0; p < 4; ++p)
            gload16(gp[p] + t * 32, &S[b][(size_t)(tid + 256 * p) * 8]);
    };

    STAGE(0, 0);
    STAGE(1, 1);
    asm volatile("s_waitcnt vmcnt(4)" ::: "memory");
    __builtin_amdgcn_s_barrier();
    asm volatile("" ::: "memory");

    for (int t = 0; t < 4; ++t) {
        if (t + 2 < 4) STAGE(t + 2, (t + 2) % 3);
        const u16* Sb = S[t % 3];
        bf16x8 a[4], b[4];
#pragma unroll
        for (int m = 0; m < 4; ++m) {
            int rw = wr + m * 16 + r;
            a[m] = *(const bf16x8*)&Sb[rw * 32 + ((s4 ^ ((rw >> 1) & 3)) << 3)];
        }
#pragma unroll
        for (int n = 0; n < 4; ++n) {
            int cB = wcb + n * 16 + r;
            b[n] = *(const bf16x8*)&Sb[4096 + cB * 32 + ((s4 ^ ((cB >> 1) & 3)) << 3)];
        }
#pragma unroll
        for (int m = 0; m < 4; ++m)
#pragma unroll
            for (int n = 0; n < 4; ++n)
                acc[m][n] = __builtin_amdgcn_mfma_f32_16x16x32_bf16(a[m], b[n], acc[m][n], 0, 0, 0);
        if (t < 3) {
            if (t + 2 < 4) asm volatile("s_waitcnt vmcnt(4)" ::: "memory");
            else           asm volatile("s_waitcnt vmcnt(0)" ::: "memory");
            __builtin_amdgcn_s_barrier();
            asm volatile("" ::: "memory");
        }
    }

    u16* out = cb ? preB : preC;
    const float* bs = biasl + cb * 128;
#pragma unroll
    for (int m = 0; m < 4; ++m)
#pragma unroll
        for (int n = 0; n < 4; ++n) {
            int gcol = wcb + n * 16 + r;
            float bv = bs[gcol];
#pragma unroll
            for (int j = 0; j < 4; ++j) {
                int grow = row0 + wr + m * 16 + s4 * 4 + j;
                out[(size_t)grow * 128 + gcol] = f2bf(acc[m][n][j] + bv);
            }
        }
}

// ---------------- comb2: 128-row tile, depth-2 counted-vmcnt comb GEMM ----------------

template <bool OUT>
__global__ __launch_bounds__(256) void comb2(
    const u16* __restrict__ xin,        // [MROWS][128]
    const u16* __restrict__ aggb,       // [MROWS][640]
    const u16* __restrict__ BtK,        // [384][768], row = g*128 + outcol
    const float* __restrict__ bias,     // bcomb 128
    const float* __restrict__ amp, const float* __restrict__ att,
    u16* __restrict__ xout,             // [MROWS][128]  (!OUT)
    const float* __restrict__ Wout,     // [128]         (OUT)
    const float* __restrict__ bout,     // [1]           (OUT)
    float* __restrict__ y) {            // [NN]          (OUT)
    __shared__ u16 S[3][10240];         // 3 x 20 KB: A 128x32 @0, B 192x32 @4096 (u16)
    int g = blockIdx.x;
    int row = (g >> 4) * 8 + (g & 7);
    if (row >= 157) return;
    int row0 = row * 128;
    int cb = (g >> 3) & 1;              // 64-col half
    int tid = threadIdx.x;
    int w = tid >> 6, lane = tid & 63;
    int r = lane & 15, s4 = lane >> 4;
    int wr = (w >> 1) * 64, wc = (w & 1) * 32;

    int rtA0 = tid >> 2, qA = tid & 3;
    int rtA1 = rtA0 + 64;
    int koffA0 = (qA ^ ((rtA0 >> 1) & 3)) << 3;
    int koffA1 = (qA ^ ((rtA1 >> 1) & 3)) << 3;
    const u16* xA0 = xin + (size_t)(row0 + rtA0) * 128 + koffA0;
    const u16* xA1 = xin + (size_t)(row0 + rtA1) * 128 + koffA1;
    const u16* gA0 = aggb + (size_t)(row0 + rtA0) * 640 + koffA0 - 128;
    const u16* gA1 = aggb + (size_t)(row0 + rtA1) * 640 + koffA1 - 128;
    const u16* bB[3];
#pragma unroll
    for (int p = 2; p < 5; ++p) {
        int lid = tid + 256 * p;
        int rt = lid >> 2, q = lid & 3;
        int rb = rt - 128, gg = rb >> 6, jj = rb & 63;
        int koff = (q ^ ((rt >> 1) & 3)) << 3;
        bB[p - 2] = BtK + (size_t)(gg * 128 + cb * 64 + jj) * 768 + koff;
    }

    f32x4 acc[4][3][2];
#pragma unroll
    for (int m = 0; m < 4; ++m)
#pragma unroll
        for (int gg = 0; gg < 3; ++gg)
#pragma unroll
            for (int n = 0; n < 2; ++n) acc[m][gg][n] = (f32x4){0.f, 0.f, 0.f, 0.f};

    auto STAGE = [&](int t, int b) {
        const u16* a0 = (t < 4) ? (xA0 + t * 32) : (gA0 + t * 32);
        const u16* a1 = (t < 4) ? (xA1 + t * 32) : (gA1 + t * 32);
        gload16(a0, &S[b][(size_t)tid * 8]);
        gload16(a1, &S[b][(size_t)(tid + 256) * 8]);
#pragma unroll
        for (int p = 2; p < 5; ++p)
            gload16(bB[p - 2] + t * 32, &S[b][(size_t)(tid + 256 * p) * 8]);
    };

    STAGE(0, 0);
    STAGE(1, 1);
    asm volatile("s_waitcnt vmcnt(5)" ::: "memory");
    __builtin_amdgcn_s_barrier();
    asm volatile("" ::: "memory");

    int buf = 0;
    for (int t = 0; t < 24; ++t) {
        if (t + 2 < 24) STAGE(t + 2, (t + 2) % 3);
        const u16* Sb = S[buf];
        bf16x8 a[4];
#pragma unroll
        for (int m = 0; m < 4; ++m) {
            int rw = wr + m * 16 + r;
            a[m] = *(const bf16x8*)&Sb[rw * 32 + ((s4 ^ ((rw >> 1) & 3)) << 3)];
        }
#pragma unroll
        for (int gg = 0; gg < 3; ++gg) {
            if (gg > 0 && t < 4) continue;       // zero B-block for k<128
#pragma unroll
            for (int n = 0; n < 2; ++n) {
                int rb = gg * 64 + wc + n * 16 + r;
                bf16x8 b = *(const bf16x8*)&Sb[4096 + rb * 32 + ((s4 ^ ((rb >> 1) & 3)) << 3)];
#pragma unroll
                for (int m = 0; m < 4; ++m)
                    acc[m][gg][n] = __builtin_amdgcn_mfma_f32_16x16x32_bf16(a[m], b, acc[m][gg][n], 0, 0, 0);
            }
        }
        if (t < 23) {
            if (t + 2 < 24) asm volatile("s_waitcnt vmcnt(5)" ::: "memory");
            else            asm volatile("s_waitcnt vmcnt(0)" ::: "memory");
            __builtin_amdgcn_s_barrier();
            asm volatile("" ::: "memory");
        }
        buf = (buf == 2) ? 0 : buf + 1;
    }

    int gcb = cb * 64 + wc;
#pragma unroll
    for (int m = 0; m < 4; ++m)
#pragma unroll
        for (int j = 0; j < 4; ++j) {
            int grow = row0 + wr + m * 16 + s4 * 4 + j;
            if (grow >= NN) continue;
            float av = amp[grow], tv = att[grow];
            if (OUT) {
                float ps = 0.f;
#pragma unroll
                for (int n = 0; n < 2; ++n) {
                    int gcol = gcb + n * 16 + r;
                    float v = acc[m][0][n][j] + av * acc[m][1][n][j] + tv * acc[m][2][n][j] + bias[gcol];
                    v = fmaxf(v, 0.f);
                    ps = fmaf(v, Wout[gcol], ps);
                }
                ps += __shfl_xor(ps, 1, 16);
                ps += __shfl_xor(ps, 2, 16);
                ps += __shfl_xor(ps, 4, 16);
                ps += __shfl_xor(ps, 8, 16);
                if (r == 0) {
                    if (cb == 0 && wc == 0) ps += bout[0];
                    atomicAdd(&y[grow], ps);
                }
            } else {
#pragma unroll
                for (int n = 0; n < 2; ++n) {
                    int gcol = gcb + n * 16 + r;
                    float v = acc[m][0][n][j] + av * acc[m][1][n][j] + tv * acc[m][2][n][j] + bias[gcol];
                    v = fmaxf(v, 0.f);
                    xout[(size_t)grow * F + gcol] = f2bf(v);
                }
            }
        }
}

// ---------------- host ----------------

extern "C" void kernel_launch(void* const* d_in, const int* in_sizes, int n_in,
                              void* d_out, int out_size, void* d_ws, size_t ws_size,
                              hipStream_t stream) {
    const float* x_in   = (const float*)d_in[0];
    const int*   ei     = (const int*)d_in[1];
    const float* W_pre  = (const float*)d_in[2];
    const float* b_pre  = (const float*)d_in[3];
    const float* W_post = (const float*)d_in[4];
    const float* b_post = (const float*)d_in[5];
    const float* W_lin  = (const float*)d_in[6];
    const float* b_lin  = (const float*)d_in[7];
    const float* W_out  = (const float*)d_in[8];
    const float* b_out  = (const float*)d_in[9];

    const int* src = ei;
    const int* dst = ei + NE;

    double sl = 0.0;
    for (int i = 0; i < 33; ++i) sl += log((double)(i + 1));
    float avg_log = (float)(sl / 33.0);

    char* ws = (char*)d_ws;
    size_t p = 0;
    auto alloc = [&](size_t bytes) { void* r = ws + p; p += (bytes + 255) & ~(size_t)255; return r; };
    u16*   xbufA   = (u16*)alloc((size_t)MROWS * F * 2);
    u16*   xbufB   = (u16*)alloc((size_t)MROWS * F * 2);
    u16*   aggb    = (u16*)alloc((size_t)MROWS * 640 * 2);
    u16*   preC    = (u16*)alloc((size_t)MROWS * F * 2);
    u16*   preB    = (u16*)alloc((size_t)MROWS * F * 2);
    u16*   WpreT   = (u16*)alloc((size_t)3 * 256 * 128 * 2);
    u16*   Wpostb  = (u16*)alloc((size_t)3 * 2048 * 128 * 2);
    u16*   WlinT   = (u16*)alloc((size_t)3 * 128 * 128 * 2);
    u16*   BtK     = (u16*)alloc((size_t)3 * 384 * 768 * 2);
    float* biaspre = (float*)alloc((size_t)3 * 256 * 4);
    float* bcomb   = (float*)alloc((size_t)3 * 128 * 4);
    float* amp     = (float*)alloc((size_t)MPAD * 4);
    float* att     = (float*)alloc((size_t)MPAD * 4);
    int*   cnt     = (int*)alloc((size_t)NN * 4);
    int*   offs    = (int*)alloc((size_t)(NN + 1) * 4);
    int*   cur     = (int*)alloc((size_t)NN * 4);
    int*   csr     = (int*)alloc((size_t)NE * 4);
    int*   bsum    = (int*)alloc((size_t)SCAN_NB * 4);
    (void)ws_size;

    float* y = (float*)d_out;

    prep_all<<<(int)((P7 + 255) / 256), 256, 0, stream>>>(
        x_in, W_pre, W_lin, W_post, b_pre, b_post, b_lin,
        xbufA, WpreT, WlinT, Wpostb, biaspre, bcomb, cnt, cur, y);

    hist_kernel<<<(NE + 255) / 256, 256, 0, stream>>>(dst, cnt, NE);
    scan_p1<<<SCAN_NB, 256, 0, stream>>>(cnt, bsum);
    scan_p23<<<SCAN_NB, 256, 0, stream>>>(cnt, bsum, offs, amp, att, avg_log);
    scatter_kernel<<<(NE + 255) / 256, 256, 0, stream>>>(src, dst, offs, cur, csr, NE);

    // BtK[l] = (W_post@W_lin)^T scattered into [384][768] layout, all 3 layers
    mfma_gemm<<<dim3(2, 16, 3), 256, 0, stream>>>(
        WlinT, 128, Wpostb, 128, BtK, 128,
        16384, 262144, 294912);

    // layer-0 pre: preC/preB = x @ [Wtop|Wbot] + [b_pre|0]
    pre2<<<320, 256, 0, stream>>>(xbufA, WpreT, biaspre, preC, preB);

    u16* xc = xbufA;
    u16* xn = xbufB;
    for (int l = 0; l < NLAYER; ++l) {
        agg_kernel<<<2048, 256, 0, stream>>>(preC, preB, offs, csr, aggb);
        if (l < NLAYER - 1) {
            comb2<false><<<320, 256, 0, stream>>>(
                xc, aggb, BtK + (size_t)l * 294912, bcomb + (size_t)l * 128,
                amp, att, xn, nullptr, nullptr, nullptr);
            pre2<<<320, 256, 0, stream>>>(
                xn, WpreT + (size_t)(l + 1) * 32768, biaspre + (size_t)(l + 1) * 256,
                preC, preB);
            u16* tmp = xc; xc = xn; xn = tmp;
        } else {
            comb2<true><<<320, 256, 0, stream>>>(
                xc, aggb, BtK + (size_t)l * 294912, bcomb + (size_t)l * 128,
                amp, att, nullptr, W_out, b_out, y);
        }
    }
}

// Round 19
// 205.720 us; speedup vs baseline: 1.0861x; 1.0270x over previous
//
#include <hip/hip_runtime.h>
#include <math.h>

#define NN 20000
#define NE 320000
#define F 128
#define NLAYER 3
#define MPAD 20032          // 313 * 64
#define MROWS 20096         // 157 * 128 (128-row-tile pad)
#define SCAN_NB 79          // ceil(NN/256)

typedef unsigned int u32;
typedef unsigned short u16;
typedef __attribute__((ext_vector_type(8))) short bf16x8;
typedef __attribute__((ext_vector_type(4))) float f32x4;

__device__ __forceinline__ u16 f2bf(float f) {
    union { float f; u32 u; } x{f};
    u32 r = x.u + 0x7FFFu + ((x.u >> 16) & 1u);
    return (u16)(r >> 16);
}
__device__ __forceinline__ float bflo(u32 u) { return __uint_as_float(u << 16); }
__device__ __forceinline__ float bfhi(u32 u) { return __uint_as_float(u & 0xFFFF0000u); }

__device__ __forceinline__ void gload16(const u16* g, u16* l) {
    __builtin_amdgcn_global_load_lds(
        (const __attribute__((address_space(1))) void*)g,
        (__attribute__((address_space(3))) void*)l, 16, 0, 0);
}

// ---------------- graph-structure kernels ----------------

__global__ void hist_kernel(const int* __restrict__ dst, int* __restrict__ cnt, int e) {
    int i = blockIdx.x * blockDim.x + threadIdx.x;
    if (i < e) atomicAdd(&cnt[dst[i]], 1);
}

__global__ void scan_p1(const int* __restrict__ cnt, int* __restrict__ bsum) {
    __shared__ int sh[256];
    int i = blockIdx.x * 256 + threadIdx.x;
    int t = threadIdx.x;
    sh[t] = (i < NN) ? cnt[i] : 0;
    __syncthreads();
#pragma unroll
    for (int d = 128; d > 0; d >>= 1) {
        if (t < d) sh[t] += sh[t + d];
        __syncthreads();
    }
    if (t == 0) bsum[blockIdx.x] = sh[0];
}

// merged p2+p3: every block scans the 79 block sums redundantly in LDS
__global__ void scan_p23(const int* __restrict__ cnt, const int* __restrict__ bsum,
                         int* __restrict__ off, float* __restrict__ amp,
                         float* __restrict__ att, float avg_log) {
    __shared__ int sh[256];
    __shared__ int sb[128];
    int i = blockIdx.x * 256 + threadIdx.x;
    int t = threadIdx.x;
    if (t < 128) sb[t] = (t < SCAN_NB) ? bsum[t] : 0;
    __syncthreads();
#pragma unroll
    for (int d = 1; d < 128; d <<= 1) {
        int x = (t >= d && t < 128) ? sb[t - d] : 0;
        __syncthreads();
        if (t < 128) sb[t] += x;
        __syncthreads();
    }
    int base = (blockIdx.x == 0) ? 0 : sb[blockIdx.x - 1];
    int v = (i < NN) ? cnt[i] : 0;
    sh[t] = v;
    __syncthreads();
#pragma unroll
    for (int d = 1; d < 256; d <<= 1) {
        int x = (t >= d) ? sh[t - d] : 0;
        __syncthreads();
        sh[t] += x;
        __syncthreads();
    }
    if (i < NN) {
        int incl = sh[t] + base;
        off[i] = incl - v;
        if (i == NN - 1) off[NN] = incl;
        float deg = fmaxf((float)v, 1.0f);
        float ld = logf(deg + 1.0f);
        amp[i] = ld / avg_log;
        att[i] = avg_log / ld;
    }
}

__global__ void scatter_kernel(const int* __restrict__ src, const int* __restrict__ dst,
                               const int* __restrict__ off, int* __restrict__ cur,
                               int* __restrict__ csr, int e) {
    int i = blockIdx.x * blockDim.x + threadIdx.x;
    if (i < e) {
        int d = dst[i];
        int p = atomicAdd(&cur[d], 1);
        csr[off[d] + p] = src[i];
    }
}

// ---------------- combined prep: converts + biases + zero-fills, flat-indexed ----------------

#define P0 640000L                      // xbuf NN*F/4 (float4-vectorized)
#define P1 (P0 + 3L * 256 * 128)        // wpreT (strided transpose, scalar)
#define P2 (P1 + 3L * 128 * 128)        // wlinT (strided transpose, scalar)
#define P3 (P2 + 3L * 2048 * 128 / 4)   // wpost (contiguous, float4-vectorized)
#define P4 (P3 + 3L * 256)              // biaspre
#define P5 (P4 + 3L * 128)              // bcomb
#define P6 (P5 + 2L * NN)               // cnt/cur zero
#define P7 (P6 + NN)                    // y zero

__global__ void prep_all(const float* __restrict__ x, const float* __restrict__ W_pre,
                         const float* __restrict__ W_lin, const float* __restrict__ W_post,
                         const float* __restrict__ b_pre, const float* __restrict__ b_post,
                         const float* __restrict__ b_lin,
                         u16* __restrict__ xbuf,
                         u16* __restrict__ WpreT, u16* __restrict__ WlinT,
                         u16* __restrict__ Wpostb, float* __restrict__ biaspre,
                         float* __restrict__ bcomb,
                         int* __restrict__ cnt, int* __restrict__ cur,
                         float* __restrict__ y) {
    long i = (long)blockIdx.x * 256 + threadIdx.x;
    if (i < P0) {
        float4 v = *(const float4*)&x[i * 4];
        u16 h[4] = {f2bf(v.x), f2bf(v.y), f2bf(v.z), f2bf(v.w)};
        *(ulong1*)&xbuf[i * 4] = *(ulong1*)h;
    } else if (i < P1) {
        long j = i - P0;
        int l = j / 32768, t = j % 32768;
        int c = t >> 7, k = t & 127;
        int si = (c < 128) ? (k * 128 + c) : ((k + 128) * 128 + (c - 128));
        WpreT[l * 32768 + t] = f2bf(W_pre[l * 32768 + si]);
    } else if (i < P2) {
        long j = i - P1;
        int l = j / 16384, t = j % 16384;
        int c = t >> 7, k = t & 127;
        WlinT[l * 16384 + t] = f2bf(W_lin[l * 16384 + k * 128 + c]);
    } else if (i < P3) {
        long j = i - P2;
        float4 v = *(const float4*)&W_post[j * 4];
        u16 h[4] = {f2bf(v.x), f2bf(v.y), f2bf(v.z), f2bf(v.w)};
        *(ulong1*)&Wpostb[j * 4] = *(ulong1*)h;
    } else if (i < P4) {
        long j = i - P3;
        int l = j / 256, t = j % 256;
        biaspre[l * 256 + t] = (t < 128) ? b_pre[l * 128 + t] : 0.f;
    } else if (i < P5) {
        long j = i - P4;
        int l = j / 128, t = j % 128;
        float s = b_lin[l * 128 + t];
        for (int c = 0; c < 128; ++c) s += b_post[l * 128 + c] * W_lin[l * 16384 + c * 128 + t];
        bcomb[l * 128 + t] = s;
    } else if (i < P6) {
        long j = i - P5;
        if (j < NN) cnt[j] = 0; else cur[j - NN] = 0;
    } else if (i < P7) {
        y[i - P6] = 0.f;
    }
}

// ---------------- aggregation: persistent grid, one WAVE per node ----------------
// software-pipelined: next batch's 8 index loads issued while current gathers in flight

#define PROC(u) { float v_; \
    v_ = bflo(u); s0 += v_; q0 = fmaf(v_, v_, q0); mn0 = fminf(mn0, v_); mx0 = fmaxf(mx0, v_); \
    v_ = bfhi(u); s1 += v_; q1 = fmaf(v_, v_, q1); mn1 = fminf(mn1, v_); mx1 = fmaxf(mx1, v_); }

__global__ __launch_bounds__(256) void agg_kernel(
    const u16* __restrict__ preC, const u16* __restrict__ preB,
    const int* __restrict__ off, const int* __restrict__ csr,
    u16* __restrict__ aggb) {
    int tid = threadIdx.x, w = tid >> 6, lane = tid & 63;
    const u32* bpl = (const u32*)preB + lane;          // row stride 64 u32
    int nwaves = gridDim.x * 4;
    for (int node = blockIdx.x * 4 + w; node < NN; node += nwaves) {
        int o0 = off[node], o1 = off[node + 1];
        int deg = o1 - o0;
        float s0 = 0, s1 = 0, q0 = 0, q1 = 0;
        float mn0 = 1e30f, mn1 = 1e30f, mx0 = -1e30f, mx1 = -1e30f;
        int j = o0;
        int nb = deg >> 3;
        if (nb > 0) {
            int idx[8];
#pragma unroll
            for (int p = 0; p < 8; ++p) idx[p] = csr[j + p];
            for (int b = 1; b < nb; ++b) {
                u32 u[8];
#pragma unroll
                for (int p = 0; p < 8; ++p) u[p] = bpl[(size_t)idx[p] * 64];
#pragma unroll
                for (int p = 0; p < 8; ++p) idx[p] = csr[j + 8 * b + p];
#pragma unroll
                for (int p = 0; p < 8; ++p) PROC(u[p]);
            }
            {
                u32 u[8];
#pragma unroll
                for (int p = 0; p < 8; ++p) u[p] = bpl[(size_t)idx[p] * 64];
#pragma unroll
                for (int p = 0; p < 8; ++p) PROC(u[p]);
            }
            j += nb * 8;
        }
        if (j + 4 <= o1) {
            int i0 = csr[j], i1 = csr[j + 1], i2 = csr[j + 2], i3 = csr[j + 3];
            u32 u0 = bpl[(size_t)i0 * 64];
            u32 u1 = bpl[(size_t)i1 * 64];
            u32 u2 = bpl[(size_t)i2 * 64];
            u32 u3 = bpl[(size_t)i3 * 64];
            PROC(u0); PROC(u1); PROC(u2); PROC(u3);
            j += 4;
        }
        for (; j < o1; ++j) { u32 u = bpl[(size_t)csr[j] * 64]; PROC(u); }

        float mean0, mean1, sum0, sum1, std0, std1, lo0, lo1, hi0, hi1;
        if (deg == 0) {
            sum0 = sum1 = 0.f; mean0 = mean1 = 0.f;
            std0 = std1 = sqrtf(1e-5f);
            lo0 = lo1 = hi0 = hi1 = 0.f;
        } else {
            u32 uc = ((const u32*)preC)[(size_t)node * 64 + lane];
            float c0 = bflo(uc), c1 = bfhi(uc), dg = (float)deg;
            sum0 = dg * c0 + s0; mean0 = sum0 / dg;
            sum1 = dg * c1 + s1; mean1 = sum1 / dg;
            float msq0 = c0 * c0 + (2.f * c0 * s0 + q0) / dg;
            float msq1 = c1 * c1 + (2.f * c1 * s1 + q1) / dg;
            std0 = sqrtf(fmaxf(msq0 - mean0 * mean0, 0.f) + 1e-5f);
            std1 = sqrtf(fmaxf(msq1 - mean1 * mean1, 0.f) + 1e-5f);
            lo0 = c0 + mn0; lo1 = c1 + mn1; hi0 = c0 + mx0; hi1 = c1 + mx1;
        }
        u32* cr = (u32*)aggb + (size_t)node * 320 + lane;    // row = 640 bf16
        float f0[5] = {mean0, sum0, std0, lo0, hi0};
        float f1[5] = {mean1, sum1, std1, lo1, hi1};
#pragma unroll
        for (int a = 0; a < 5; ++a)
            cr[a * 64] = (u32)f2bf(f0[a]) | ((u32)f2bf(f1[a]) << 16);
    }
}

// ---------------- setup_gemm: fused wprod (BtK build) + layer-0 pre2 ----------------
// grid 416: blocks [0,320) run pre2 path; [320,416) run wprod path.

__device__ __forceinline__ void pre2_body(
    int g, int tid, u16 (*S)[8192],
    const u16* __restrict__ xin, const u16* __restrict__ Wp,
    const float* __restrict__ biasl,
    u16* __restrict__ preC, u16* __restrict__ preB) {
    int row = (g >> 4) * 8 + (g & 7);
    if (row >= 157) return;
    int row0 = row * 128;
    int cb = (g >> 3) & 1;
    int w = tid >> 6, lane = tid & 63;
    int r = lane & 15, s4 = lane >> 4;
    int wr = (w >> 1) * 64, wcb = (w & 1) * 64;

    const u16* gp[4];
#pragma unroll
    for (int p = 0; p < 4; ++p) {
        int lid = tid + 256 * p;
        int rt = lid >> 2, q = lid & 3;
        int koff = (q ^ ((rt >> 1) & 3)) << 3;
        if (rt < 128) gp[p] = xin + (size_t)(row0 + rt) * 128 + koff;
        else          gp[p] = Wp + (size_t)(cb * 128 + (rt - 128)) * 128 + koff;
    }

    f32x4 acc[4][4];
#pragma unroll
    for (int m = 0; m < 4; ++m)
#pragma unroll
        for (int n = 0; n < 4; ++n) acc[m][n] = (f32x4){0.f, 0.f, 0.f, 0.f};

    auto STAGE = [&](int t, int b) {
#pragma unroll
        for (int p = 0; p < 4; ++p)
            gload16(gp[p] + t * 32, &S[b][(size_t)(tid + 256 * p) * 8]);
    };

    STAGE(0, 0);
    STAGE(1, 1);
    asm volatile("s_waitcnt vmcnt(4)" ::: "memory");
    __builtin_amdgcn_s_barrier();
    asm volatile("" ::: "memory");

    for (int t = 0; t < 4; ++t) {
        if (t + 2 < 4) STAGE(t + 2, (t + 2) % 3);
        const u16* Sb = S[t % 3];
        bf16x8 a[4], b[4];
#pragma unroll
        for (int m = 0; m < 4; ++m) {
            int rw = wr + m * 16 + r;
            a[m] = *(const bf16x8*)&Sb[rw * 32 + ((s4 ^ ((rw >> 1) & 3)) << 3)];
        }
#pragma unroll
        for (int n = 0; n < 4; ++n) {
            int cB = wcb + n * 16 + r;
            b[n] = *(const bf16x8*)&Sb[4096 + cB * 32 + ((s4 ^ ((cB >> 1) & 3)) << 3)];
        }
#pragma unroll
        for (int m = 0; m < 4; ++m)
#pragma unroll
            for (int n = 0; n < 4; ++n)
                acc[m][n] = __builtin_amdgcn_mfma_f32_16x16x32_bf16(a[m], b[n], acc[m][n], 0, 0, 0);
        if (t < 3) {
            if (t + 2 < 4) asm volatile("s_waitcnt vmcnt(4)" ::: "memory");
            else           asm volatile("s_waitcnt vmcnt(0)" ::: "memory");
            __builtin_amdgcn_s_barrier();
            asm volatile("" ::: "memory");
        }
    }

    u16* out = cb ? preB : preC;
    const float* bs = biasl + cb * 128;
#pragma unroll
    for (int m = 0; m < 4; ++m)
#pragma unroll
        for (int n = 0; n < 4; ++n) {
            int gcol = wcb + n * 16 + r;
            float bv = bs[gcol];
#pragma unroll
            for (int j = 0; j < 4; ++j) {
                int grow = row0 + wr + m * 16 + s4 * 4 + j;
                out[(size_t)grow * 128 + gcol] = f2bf(acc[m][n][j] + bv);
            }
        }
}

__device__ __forceinline__ void wprod_body(
    int b, int tid, u16* As, u16* Bs,
    const u16* __restrict__ WlinT, const u16* __restrict__ Wpostb,
    u16* __restrict__ BtK) {
    int z = b >> 5, rem = b & 31;
    int row0 = (rem & 1) * 64, col0 = (rem >> 1) * 128;
    const u16* A = WlinT + (size_t)z * 16384;
    const u16* Bt = Wpostb + (size_t)z * 262144;
    u16* C = BtK + (size_t)z * 294912;
    const int lda = 128, K = 128, Mreal = 128;
    int w = tid >> 6, lane = tid & 63;

    int arow = tid >> 2, asl = tid & 3;
    const u16* agp = A + (size_t)(row0 + arow) * lda + ((asl ^ ((arow >> 1) & 3)) << 3);
    u16* alds = As + w * 512;
    int br0 = tid >> 2;
    int br1 = 64 + (tid >> 2);
    const u16* bgp0 = Bt + (size_t)(col0 + br0) * K + (((tid & 3) ^ ((br0 >> 1) & 3)) << 3);
    const u16* bgp1 = Bt + (size_t)(col0 + br1) * K + (((tid & 3) ^ ((br1 >> 1) & 3)) << 3);
    u16* blds0 = Bs + w * 512;
    u16* blds1 = Bs + 2048 + w * 512;

    f32x4 acc[2][4];
#pragma unroll
    for (int m = 0; m < 2; ++m)
#pragma unroll
        for (int n = 0; n < 4; ++n) acc[m][n] = (f32x4){0.f, 0.f, 0.f, 0.f};

    int s = lane >> 4, r = lane & 15;
    int wr = (w >> 1) * 32, wc = (w & 1) * 64;

    for (int k0 = 0; k0 < K; k0 += 32) {
        gload16(agp + k0, alds);
        gload16(bgp0 + k0, blds0);
        gload16(bgp1 + k0, blds1);
        __syncthreads();
        bf16x8 a[2], bb[4];
#pragma unroll
        for (int m = 0; m < 2; ++m) {
            int row = wr + m * 16 + r;
            a[m] = *(const bf16x8*)&As[row * 32 + ((s ^ ((row >> 1) & 3)) << 3)];
        }
#pragma unroll
        for (int n = 0; n < 4; ++n) {
            int col = wc + n * 16 + r;
            bb[n] = *(const bf16x8*)&Bs[col * 32 + ((s ^ ((col >> 1) & 3)) << 3)];
        }
#pragma unroll
        for (int m = 0; m < 2; ++m)
#pragma unroll
            for (int n = 0; n < 4; ++n)
                acc[m][n] = __builtin_amdgcn_mfma_f32_16x16x32_bf16(a[m], bb[n], acc[m][n], 0, 0, 0);
        __syncthreads();
    }

#pragma unroll
    for (int m = 0; m < 2; ++m) {
#pragma unroll
        for (int n = 0; n < 4; ++n) {
            int gcol = col0 + wc + n * 16 + r;
#pragma unroll
            for (int j = 0; j < 4; ++j) {
                int grow = row0 + wr + m * 16 + s * 4 + j;
                if (grow < Mreal) {
                    u16 h = f2bf(acc[m][n][j]);
                    size_t idx;
                    if (gcol < 128) idx = (size_t)grow * 768 + gcol;
                    else {
                        int t2 = gcol - 128;
                        int gg = t2 / 640;
                        int ko = 128 + t2 - gg * 640;
                        idx = (size_t)(gg * 128 + grow) * 768 + ko;
                    }
                    C[idx] = h;
                }
            }
        }
    }
}

__global__ __launch_bounds__(256) void setup_gemm(
    const u16* __restrict__ xin, const u16* __restrict__ Wp,
    const float* __restrict__ biasl,
    u16* __restrict__ preC, u16* __restrict__ preB,
    const u16* __restrict__ WlinT, const u16* __restrict__ Wpostb,
    u16* __restrict__ BtK) {
    __shared__ u16 S[3][8192];
    int bx = blockIdx.x, tid = threadIdx.x;
    if (bx < 320) pre2_body(bx, tid, S, xin, Wp, biasl, preC, preB);
    else          wprod_body(bx - 320, tid, S[0], S[0] + 2048, WlinT, Wpostb, BtK);
}

// ---------------- pre2: 128-row tile, depth-2 counted-vmcnt pre GEMM ----------------

__global__ __launch_bounds__(256) void pre2(
    const u16* __restrict__ xin,        // [MROWS][128]
    const u16* __restrict__ Wp,         // WpreT layer base [256][128]
    const float* __restrict__ biasl,    // biaspre layer base [256]
    u16* __restrict__ preC, u16* __restrict__ preB) {
    __shared__ u16 S[3][8192];
    pre2_body(blockIdx.x, threadIdx.x, S, xin, Wp, biasl, preC, preB);
}

// ---------------- comb2: 128-row tile, depth-2 counted-vmcnt comb GEMM ----------------

template <bool OUT>
__global__ __launch_bounds__(256) void comb2(
    const u16* __restrict__ xin,        // [MROWS][128]
    const u16* __restrict__ aggb,       // [MROWS][640]
    const u16* __restrict__ BtK,        // [384][768], row = g*128 + outcol
    const float* __restrict__ bias,     // bcomb 128
    const float* __restrict__ amp, const float* __restrict__ att,
    u16* __restrict__ xout,             // [MROWS][128]  (!OUT)
    const float* __restrict__ Wout,     // [128]         (OUT)
    const float* __restrict__ bout,     // [1]           (OUT)
    float* __restrict__ y) {            // [NN]          (OUT)
    __shared__ u16 S[3][10240];         // 3 x 20 KB: A 128x32 @0, B 192x32 @4096 (u16)
    int g = blockIdx.x;
    int row = (g >> 4) * 8 + (g & 7);
    if (row >= 157) return;
    int row0 = row * 128;
    int cb = (g >> 3) & 1;              // 64-col half
    int tid = threadIdx.x;
    int w = tid >> 6, lane = tid & 63;
    int r = lane & 15, s4 = lane >> 4;
    int wr = (w >> 1) * 64, wc = (w & 1) * 32;

    int rtA0 = tid >> 2, qA = tid & 3;
    int rtA1 = rtA0 + 64;
    int koffA0 = (qA ^ ((rtA0 >> 1) & 3)) << 3;
    int koffA1 = (qA ^ ((rtA1 >> 1) & 3)) << 3;
    const u16* xA0 = xin + (size_t)(row0 + rtA0) * 128 + koffA0;
    const u16* xA1 = xin + (size_t)(row0 + rtA1) * 128 + koffA1;
    const u16* gA0 = aggb + (size_t)(row0 + rtA0) * 640 + koffA0 - 128;
    const u16* gA1 = aggb + (size_t)(row0 + rtA1) * 640 + koffA1 - 128;
    const u16* bB[3];
#pragma unroll
    for (int p = 2; p < 5; ++p) {
        int lid = tid + 256 * p;
        int rt = lid >> 2, q = lid & 3;
        int rb = rt - 128, gg = rb >> 6, jj = rb & 63;
        int koff = (q ^ ((rt >> 1) & 3)) << 3;
        bB[p - 2] = BtK + (size_t)(gg * 128 + cb * 64 + jj) * 768 + koff;
    }

    f32x4 acc[4][3][2];
#pragma unroll
    for (int m = 0; m < 4; ++m)
#pragma unroll
        for (int gg = 0; gg < 3; ++gg)
#pragma unroll
            for (int n = 0; n < 2; ++n) acc[m][gg][n] = (f32x4){0.f, 0.f, 0.f, 0.f};

    auto STAGE = [&](int t, int b) {
        const u16* a0 = (t < 4) ? (xA0 + t * 32) : (gA0 + t * 32);
        const u16* a1 = (t < 4) ? (xA1 + t * 32) : (gA1 + t * 32);
        gload16(a0, &S[b][(size_t)tid * 8]);
        gload16(a1, &S[b][(size_t)(tid + 256) * 8]);
#pragma unroll
        for (int p = 2; p < 5; ++p)
            gload16(bB[p - 2] + t * 32, &S[b][(size_t)(tid + 256 * p) * 8]);
    };

    STAGE(0, 0);
    STAGE(1, 1);
    asm volatile("s_waitcnt vmcnt(5)" ::: "memory");
    __builtin_amdgcn_s_barrier();
    asm volatile("" ::: "memory");

    int buf = 0;
    for (int t = 0; t < 24; ++t) {
        if (t + 2 < 24) STAGE(t + 2, (t + 2) % 3);
        const u16* Sb = S[buf];
        bf16x8 a[4];
#pragma unroll
        for (int m = 0; m < 4; ++m) {
            int rw = wr + m * 16 + r;
            a[m] = *(const bf16x8*)&Sb[rw * 32 + ((s4 ^ ((rw >> 1) & 3)) << 3)];
        }
#pragma unroll
        for (int gg = 0; gg < 3; ++gg) {
            if (gg > 0 && t < 4) continue;       // zero B-block for k<128
#pragma unroll
            for (int n = 0; n < 2; ++n) {
                int rb = gg * 64 + wc + n * 16 + r;
                bf16x8 b = *(const bf16x8*)&Sb[4096 + rb * 32 + ((s4 ^ ((rb >> 1) & 3)) << 3)];
#pragma unroll
                for (int m = 0; m < 4; ++m)
                    acc[m][gg][n] = __builtin_amdgcn_mfma_f32_16x16x32_bf16(a[m], b, acc[m][gg][n], 0, 0, 0);
            }
        }
        if (t < 23) {
            if (t + 2 < 24) asm volatile("s_waitcnt vmcnt(5)" ::: "memory");
            else            asm volatile("s_waitcnt vmcnt(0)" ::: "memory");
            __builtin_amdgcn_s_barrier();
            asm volatile("" ::: "memory");
        }
        buf = (buf == 2) ? 0 : buf + 1;
    }

    int gcb = cb * 64 + wc;
#pragma unroll
    for (int m = 0; m < 4; ++m)
#pragma unroll
        for (int j = 0; j < 4; ++j) {
            int grow = row0 + wr + m * 16 + s4 * 4 + j;
            if (grow >= NN) continue;
            float av = amp[grow], tv = att[grow];
            if (OUT) {
                float ps = 0.f;
#pragma unroll
                for (int n = 0; n < 2; ++n) {
                    int gcol = gcb + n * 16 + r;
                    float v = acc[m][0][n][j] + av * acc[m][1][n][j] + tv * acc[m][2][n][j] + bias[gcol];
                    v = fmaxf(v, 0.f);
                    ps = fmaf(v, Wout[gcol], ps);
                }
                ps += __shfl_xor(ps, 1, 16);
                ps += __shfl_xor(ps, 2, 16);
                ps += __shfl_xor(ps, 4, 16);
                ps += __shfl_xor(ps, 8, 16);
                if (r == 0) {
                    if (cb == 0 && wc == 0) ps += bout[0];
                    atomicAdd(&y[grow], ps);
                }
            } else {
#pragma unroll
                for (int n = 0; n < 2; ++n) {
                    int gcol = gcb + n * 16 + r;
                    float v = acc[m][0][n][j] + av * acc[m][1][n][j] + tv * acc[m][2][n][j] + bias[gcol];
                    v = fmaxf(v, 0.f);
                    xout[(size_t)grow * F + gcol] = f2bf(v);
                }
            }
        }
}

// ---------------- host ----------------

extern "C" void kernel_launch(void* const* d_in, const int* in_sizes, int n_in,
                              void* d_out, int out_size, void* d_ws, size_t ws_size,
                              hipStream_t stream) {
    const float* x_in   = (const float*)d_in[0];
    const int*   ei     = (const int*)d_in[1];
    const float* W_pre  = (const float*)d_in[2];
    const float* b_pre  = (const float*)d_in[3];
    const float* W_post = (const float*)d_in[4];
    const float* b_post = (const float*)d_in[5];
    const float* W_lin  = (const float*)d_in[6];
    const float* b_lin  = (const float*)d_in[7];
    const float* W_out  = (const float*)d_in[8];
    const float* b_out  = (const float*)d_in[9];

    const int* src = ei;
    const int* dst = ei + NE;

    double sl = 0.0;
    for (int i = 0; i < 33; ++i) sl += log((double)(i + 1));
    float avg_log = (float)(sl / 33.0);

    char* ws = (char*)d_ws;
    size_t p = 0;
    auto alloc = [&](size_t bytes) { void* r = ws + p; p += (bytes + 255) & ~(size_t)255; return r; };
    u16*   xbufA   = (u16*)alloc((size_t)MROWS * F * 2);
    u16*   xbufB   = (u16*)alloc((size_t)MROWS * F * 2);
    u16*   aggb    = (u16*)alloc((size_t)MROWS * 640 * 2);
    u16*   preC    = (u16*)alloc((size_t)MROWS * F * 2);
    u16*   preB    = (u16*)alloc((size_t)MROWS * F * 2);
    u16*   WpreT   = (u16*)alloc((size_t)3 * 256 * 128 * 2);
    u16*   Wpostb  = (u16*)alloc((size_t)3 * 2048 * 128 * 2);
    u16*   WlinT   = (u16*)alloc((size_t)3 * 128 * 128 * 2);
    u16*   BtK     = (u16*)alloc((size_t)3 * 384 * 768 * 2);
    float* biaspre = (float*)alloc((size_t)3 * 256 * 4);
    float* bcomb   = (float*)alloc((size_t)3 * 128 * 4);
    float* amp     = (float*)alloc((size_t)MPAD * 4);
    float* att     = (float*)alloc((size_t)MPAD * 4);
    int*   cnt     = (int*)alloc((size_t)NN * 4);
    int*   offs    = (int*)alloc((size_t)(NN + 1) * 4);
    int*   cur     = (int*)alloc((size_t)NN * 4);
    int*   csr     = (int*)alloc((size_t)NE * 4);
    int*   bsum    = (int*)alloc((size_t)SCAN_NB * 4);
    (void)ws_size;

    float* y = (float*)d_out;

    prep_all<<<(int)((P7 + 255) / 256), 256, 0, stream>>>(
        x_in, W_pre, W_lin, W_post, b_pre, b_post, b_lin,
        xbufA, WpreT, WlinT, Wpostb, biaspre, bcomb, cnt, cur, y);

    hist_kernel<<<(NE + 255) / 256, 256, 0, stream>>>(dst, cnt, NE);
    scan_p1<<<SCAN_NB, 256, 0, stream>>>(cnt, bsum);
    scan_p23<<<SCAN_NB, 256, 0, stream>>>(cnt, bsum, offs, amp, att, avg_log);
    scatter_kernel<<<(NE + 255) / 256, 256, 0, stream>>>(src, dst, offs, cur, csr, NE);

    // fused: BtK build (96 blocks) + layer-0 pre (320 blocks)
    setup_gemm<<<416, 256, 0, stream>>>(
        xbufA, WpreT, biaspre, preC, preB, WlinT, Wpostb, BtK);

    u16* xc = xbufA;
    u16* xn = xbufB;
    for (int l = 0; l < NLAYER; ++l) {
        agg_kernel<<<2048, 256, 0, stream>>>(preC, preB, offs, csr, aggb);
        if (l < NLAYER - 1) {
            comb2<false><<<320, 256, 0, stream>>>(
                xc, aggb, BtK + (size_t)l * 294912, bcomb + (size_t)l * 128,
                amp, att, xn, nullptr, nullptr, nullptr);
            pre2<<<320, 256, 0, stream>>>(
                xn, WpreT + (size_t)(l + 1) * 32768, biaspre + (size_t)(l + 1) * 256,
                preC, preB);
            u16* tmp = xc; xc = xn; xn = tmp;
        } else {
            comb2<true><<<320, 256, 0, stream>>>(
                xc, aggb, BtK + (size_t)l * 294912, bcomb + (size_t)l * 128,
                amp, att, nullptr, W_out, b_out, y);
        }
    }
}

// Round 20
// 203.323 us; speedup vs baseline: 1.0990x; 1.0118x over previous
//
#include <hip/hip_runtime.h>
#include <math.h>

#define NN 20000
#define NE 320000
#define F 128
#define NLAYER 3
#define MPAD 20032          // 313 * 64
#define MROWS 20096         // 157 * 128 (128-row-tile pad)
#define SCAN_NB 79          // ceil(NN/256)

typedef unsigned int u32;
typedef unsigned short u16;
typedef __attribute__((ext_vector_type(8))) short bf16x8;
typedef __attribute__((ext_vector_type(4))) float f32x4;

__device__ __forceinline__ u16 f2bf(float f) {
    union { float f; u32 u; } x{f};
    u32 r = x.u + 0x7FFFu + ((x.u >> 16) & 1u);
    return (u16)(r >> 16);
}
__device__ __forceinline__ float bflo(u32 u) { return __uint_as_float(u << 16); }
__device__ __forceinline__ float bfhi(u32 u) { return __uint_as_float(u & 0xFFFF0000u); }

__device__ __forceinline__ void gload16(const u16* g, u16* l) {
    __builtin_amdgcn_global_load_lds(
        (const __attribute__((address_space(1))) void*)g,
        (__attribute__((address_space(3))) void*)l, 16, 0, 0);
}

// ---------------- graph-structure kernels ----------------

__global__ void hist_kernel(const int* __restrict__ dst, int* __restrict__ cnt, int e) {
    int i = blockIdx.x * blockDim.x + threadIdx.x;
    if (i < e) atomicAdd(&cnt[dst[i]], 1);
}

__global__ void scan_p1(const int* __restrict__ cnt, int* __restrict__ bsum) {
    __shared__ int sh[256];
    int i = blockIdx.x * 256 + threadIdx.x;
    int t = threadIdx.x;
    sh[t] = (i < NN) ? cnt[i] : 0;
    __syncthreads();
#pragma unroll
    for (int d = 128; d > 0; d >>= 1) {
        if (t < d) sh[t] += sh[t + d];
        __syncthreads();
    }
    if (t == 0) bsum[blockIdx.x] = sh[0];
}

// merged p2+p3: every block scans the 79 block sums redundantly in LDS
__global__ void scan_p23(const int* __restrict__ cnt, const int* __restrict__ bsum,
                         int* __restrict__ off, float* __restrict__ amp,
                         float* __restrict__ att, float avg_log) {
    __shared__ int sh[256];
    __shared__ int sb[128];
    int i = blockIdx.x * 256 + threadIdx.x;
    int t = threadIdx.x;
    if (t < 128) sb[t] = (t < SCAN_NB) ? bsum[t] : 0;
    __syncthreads();
#pragma unroll
    for (int d = 1; d < 128; d <<= 1) {
        int x = (t >= d && t < 128) ? sb[t - d] : 0;
        __syncthreads();
        if (t < 128) sb[t] += x;
        __syncthreads();
    }
    int base = (blockIdx.x == 0) ? 0 : sb[blockIdx.x - 1];
    int v = (i < NN) ? cnt[i] : 0;
    sh[t] = v;
    __syncthreads();
#pragma unroll
    for (int d = 1; d < 256; d <<= 1) {
        int x = (t >= d) ? sh[t - d] : 0;
        __syncthreads();
        sh[t] += x;
        __syncthreads();
    }
    if (i < NN) {
        int incl = sh[t] + base;
        off[i] = incl - v;
        if (i == NN - 1) off[NN] = incl;
        float deg = fmaxf((float)v, 1.0f);
        float ld = logf(deg + 1.0f);
        amp[i] = ld / avg_log;
        att[i] = avg_log / ld;
    }
}

__global__ void scatter_kernel(const int* __restrict__ src, const int* __restrict__ dst,
                               const int* __restrict__ off, int* __restrict__ cur,
                               int* __restrict__ csr, int e) {
    int i = blockIdx.x * blockDim.x + threadIdx.x;
    if (i < e) {
        int d = dst[i];
        int p = atomicAdd(&cur[d], 1);
        csr[off[d] + p] = src[i];
    }
}

// ---------------- combined prep: converts + biases + zero-fills, flat-indexed ----------------

#define P0 640000L                      // xbuf NN*F/4 (float4-vectorized)
#define P1 (P0 + 3L * 256 * 128)        // wpreT (strided transpose, scalar)
#define P2 (P1 + 3L * 128 * 128)        // wlinT (strided transpose, scalar)
#define P3 (P2 + 3L * 2048 * 128 / 4)   // wpost (contiguous, float4-vectorized)
#define P4 (P3 + 3L * 256)              // biaspre
#define P5 (P4 + 3L * 128 * 32)         // bcomb: 32 lanes per output, shfl reduce
#define P6 (P5 + 2L * NN)               // cnt/cur zero
#define P7 (P6 + NN)                    // y zero

__global__ void prep_all(const float* __restrict__ x, const float* __restrict__ W_pre,
                         const float* __restrict__ W_lin, const float* __restrict__ W_post,
                         const float* __restrict__ b_pre, const float* __restrict__ b_post,
                         const float* __restrict__ b_lin,
                         u16* __restrict__ xbuf,
                         u16* __restrict__ WpreT, u16* __restrict__ WlinT,
                         u16* __restrict__ Wpostb, float* __restrict__ biaspre,
                         float* __restrict__ bcomb,
                         int* __restrict__ cnt, int* __restrict__ cur,
                         float* __restrict__ y) {
    long i = (long)blockIdx.x * 256 + threadIdx.x;
    if (i < P0) {
        float4 v = *(const float4*)&x[i * 4];
        u16 h[4] = {f2bf(v.x), f2bf(v.y), f2bf(v.z), f2bf(v.w)};
        *(ulong1*)&xbuf[i * 4] = *(ulong1*)h;
    } else if (i < P1) {
        long j = i - P0;
        int l = j / 32768, t = j % 32768;
        int c = t >> 7, k = t & 127;
        int si = (c < 128) ? (k * 128 + c) : ((k + 128) * 128 + (c - 128));
        WpreT[l * 32768 + t] = f2bf(W_pre[l * 32768 + si]);
    } else if (i < P2) {
        long j = i - P1;
        int l = j / 16384, t = j % 16384;
        int c = t >> 7, k = t & 127;
        WlinT[l * 16384 + t] = f2bf(W_lin[l * 16384 + k * 128 + c]);
    } else if (i < P3) {
        long j = i - P2;
        float4 v = *(const float4*)&W_post[j * 4];
        u16 h[4] = {f2bf(v.x), f2bf(v.y), f2bf(v.z), f2bf(v.w)};
        *(ulong1*)&Wpostb[j * 4] = *(ulong1*)h;
    } else if (i < P4) {
        long j = i - P3;
        int l = j / 256, t = j % 256;
        biaspre[l * 256 + t] = (t < 128) ? b_pre[l * 128 + t] : 0.f;
    } else if (i < P5) {
        long j = i - P4;                 // section is 64-aligned; 32-lane groups intact
        int out = (int)(j >> 5), k = (int)(j & 31);
        int l = out >> 7, t = out & 127;
        float s = 0.f;
#pragma unroll
        for (int q = 0; q < 4; ++q) {
            int c = k + q * 32;
            s = fmaf(b_post[l * 128 + c], W_lin[l * 16384 + c * 128 + t], s);
        }
        s += __shfl_xor(s, 16, 32);
        s += __shfl_xor(s, 8, 32);
        s += __shfl_xor(s, 4, 32);
        s += __shfl_xor(s, 2, 32);
        s += __shfl_xor(s, 1, 32);
        if (k == 0) bcomb[out] = s + b_lin[out];
    } else if (i < P6) {
        long j = i - P5;
        if (j < NN) cnt[j] = 0; else cur[j - NN] = 0;
    } else if (i < P7) {
        y[i - P6] = 0.f;
    }
}

// ---------------- aggregation: persistent grid, one WAVE per node ----------------
// software-pipelined: next batch's 8 index loads issued while current gathers in flight

#define PROC(u) { float v_; \
    v_ = bflo(u); s0 += v_; q0 = fmaf(v_, v_, q0); mn0 = fminf(mn0, v_); mx0 = fmaxf(mx0, v_); \
    v_ = bfhi(u); s1 += v_; q1 = fmaf(v_, v_, q1); mn1 = fminf(mn1, v_); mx1 = fmaxf(mx1, v_); }

__global__ __launch_bounds__(256) void agg_kernel(
    const u16* __restrict__ preC, const u16* __restrict__ preB,
    const int* __restrict__ off, const int* __restrict__ csr,
    u16* __restrict__ aggb) {
    int tid = threadIdx.x, w = tid >> 6, lane = tid & 63;
    const u32* bpl = (const u32*)preB + lane;          // row stride 64 u32
    int nwaves = gridDim.x * 4;
    for (int node = blockIdx.x * 4 + w; node < NN; node += nwaves) {
        int o0 = off[node], o1 = off[node + 1];
        int deg = o1 - o0;
        float s0 = 0, s1 = 0, q0 = 0, q1 = 0;
        float mn0 = 1e30f, mn1 = 1e30f, mx0 = -1e30f, mx1 = -1e30f;
        int j = o0;
        int nb = deg >> 3;
        if (nb > 0) {
            int idx[8];
#pragma unroll
            for (int p = 0; p < 8; ++p) idx[p] = csr[j + p];
            for (int b = 1; b < nb; ++b) {
                u32 u[8];
#pragma unroll
                for (int p = 0; p < 8; ++p) u[p] = bpl[(size_t)idx[p] * 64];
#pragma unroll
                for (int p = 0; p < 8; ++p) idx[p] = csr[j + 8 * b + p];
#pragma unroll
                for (int p = 0; p < 8; ++p) PROC(u[p]);
            }
            {
                u32 u[8];
#pragma unroll
                for (int p = 0; p < 8; ++p) u[p] = bpl[(size_t)idx[p] * 64];
#pragma unroll
                for (int p = 0; p < 8; ++p) PROC(u[p]);
            }
            j += nb * 8;
        }
        if (j + 4 <= o1) {
            int i0 = csr[j], i1 = csr[j + 1], i2 = csr[j + 2], i3 = csr[j + 3];
            u32 u0 = bpl[(size_t)i0 * 64];
            u32 u1 = bpl[(size_t)i1 * 64];
            u32 u2 = bpl[(size_t)i2 * 64];
            u32 u3 = bpl[(size_t)i3 * 64];
            PROC(u0); PROC(u1); PROC(u2); PROC(u3);
            j += 4;
        }
        for (; j < o1; ++j) { u32 u = bpl[(size_t)csr[j] * 64]; PROC(u); }

        float mean0, mean1, sum0, sum1, std0, std1, lo0, lo1, hi0, hi1;
        if (deg == 0) {
            sum0 = sum1 = 0.f; mean0 = mean1 = 0.f;
            std0 = std1 = sqrtf(1e-5f);
            lo0 = lo1 = hi0 = hi1 = 0.f;
        } else {
            u32 uc = ((const u32*)preC)[(size_t)node * 64 + lane];
            float c0 = bflo(uc), c1 = bfhi(uc), dg = (float)deg;
            sum0 = dg * c0 + s0; mean0 = sum0 / dg;
            sum1 = dg * c1 + s1; mean1 = sum1 / dg;
            float msq0 = c0 * c0 + (2.f * c0 * s0 + q0) / dg;
            float msq1 = c1 * c1 + (2.f * c1 * s1 + q1) / dg;
            std0 = sqrtf(fmaxf(msq0 - mean0 * mean0, 0.f) + 1e-5f);
            std1 = sqrtf(fmaxf(msq1 - mean1 * mean1, 0.f) + 1e-5f);
            lo0 = c0 + mn0; lo1 = c1 + mn1; hi0 = c0 + mx0; hi1 = c1 + mx1;
        }
        u32* cr = (u32*)aggb + (size_t)node * 320 + lane;    // row = 640 bf16
        float f0[5] = {mean0, sum0, std0, lo0, hi0};
        float f1[5] = {mean1, sum1, std1, lo1, hi1};
#pragma unroll
        for (int a = 0; a < 5; ++a)
            cr[a * 64] = (u32)f2bf(f0[a]) | ((u32)f2bf(f1[a]) << 16);
    }
}

// ---------------- setup_gemm: fused wprod (BtK build) + layer-0 pre2 ----------------
// grid 416: blocks [0,320) run pre2 path; [320,416) run wprod path.

__device__ __forceinline__ void pre2_body(
    int g, int tid, u16 (*S)[8192],
    const u16* __restrict__ xin, const u16* __restrict__ Wp,
    const float* __restrict__ biasl,
    u16* __restrict__ preC, u16* __restrict__ preB) {
    int row = (g >> 4) * 8 + (g & 7);
    if (row >= 157) return;
    int row0 = row * 128;
    int cb = (g >> 3) & 1;
    int w = tid >> 6, lane = tid & 63;
    int r = lane & 15, s4 = lane >> 4;
    int wr = (w >> 1) * 64, wcb = (w & 1) * 64;

    const u16* gp[4];
#pragma unroll
    for (int p = 0; p < 4; ++p) {
        int lid = tid + 256 * p;
        int rt = lid >> 2, q = lid & 3;
        int koff = (q ^ ((rt >> 1) & 3)) << 3;
        if (rt < 128) gp[p] = xin + (size_t)(row0 + rt) * 128 + koff;
        else          gp[p] = Wp + (size_t)(cb * 128 + (rt - 128)) * 128 + koff;
    }

    f32x4 acc[4][4];
#pragma unroll
    for (int m = 0; m < 4; ++m)
#pragma unroll
        for (int n = 0; n < 4; ++n) acc[m][n] = (f32x4){0.f, 0.f, 0.f, 0.f};

    auto STAGE = [&](int t, int b) {
#pragma unroll
        for (int p = 0; p < 4; ++p)
            gload16(gp[p] + t * 32, &S[b][(size_t)(tid + 256 * p) * 8]);
    };

    STAGE(0, 0);
    STAGE(1, 1);
    asm volatile("s_waitcnt vmcnt(4)" ::: "memory");
    __builtin_amdgcn_s_barrier();
    asm volatile("" ::: "memory");

    for (int t = 0; t < 4; ++t) {
        if (t + 2 < 4) STAGE(t + 2, (t + 2) % 3);
        const u16* Sb = S[t % 3];
        bf16x8 a[4], b[4];
#pragma unroll
        for (int m = 0; m < 4; ++m) {
            int rw = wr + m * 16 + r;
            a[m] = *(const bf16x8*)&Sb[rw * 32 + ((s4 ^ ((rw >> 1) & 3)) << 3)];
        }
#pragma unroll
        for (int n = 0; n < 4; ++n) {
            int cB = wcb + n * 16 + r;
            b[n] = *(const bf16x8*)&Sb[4096 + cB * 32 + ((s4 ^ ((cB >> 1) & 3)) << 3)];
        }
#pragma unroll
        for (int m = 0; m < 4; ++m)
#pragma unroll
            for (int n = 0; n < 4; ++n)
                acc[m][n] = __builtin_amdgcn_mfma_f32_16x16x32_bf16(a[m], b[n], acc[m][n], 0, 0, 0);
        if (t < 3) {
            if (t + 2 < 4) asm volatile("s_waitcnt vmcnt(4)" ::: "memory");
            else           asm volatile("s_waitcnt vmcnt(0)" ::: "memory");
            __builtin_amdgcn_s_barrier();
            asm volatile("" ::: "memory");
        }
    }

    u16* out = cb ? preB : preC;
    const float* bs = biasl + cb * 128;
#pragma unroll
    for (int m = 0; m < 4; ++m)
#pragma unroll
        for (int n = 0; n < 4; ++n) {
            int gcol = wcb + n * 16 + r;
            float bv = bs[gcol];
#pragma unroll
            for (int j = 0; j < 4; ++j) {
                int grow = row0 + wr + m * 16 + s4 * 4 + j;
                out[(size_t)grow * 128 + gcol] = f2bf(acc[m][n][j] + bv);
            }
        }
}

__device__ __forceinline__ void wprod_body(
    int b, int tid, u16* As, u16* Bs,
    const u16* __restrict__ WlinT, const u16* __restrict__ Wpostb,
    u16* __restrict__ BtK) {
    int z = b >> 5, rem = b & 31;
    int row0 = (rem & 1) * 64, col0 = (rem >> 1) * 128;
    const u16* A = WlinT + (size_t)z * 16384;
    const u16* Bt = Wpostb + (size_t)z * 262144;
    u16* C = BtK + (size_t)z * 294912;
    const int lda = 128, K = 128, Mreal = 128;
    int w = tid >> 6, lane = tid & 63;

    int arow = tid >> 2, asl = tid & 3;
    const u16* agp = A + (size_t)(row0 + arow) * lda + ((asl ^ ((arow >> 1) & 3)) << 3);
    u16* alds = As + w * 512;
    int br0 = tid >> 2;
    int br1 = 64 + (tid >> 2);
    const u16* bgp0 = Bt + (size_t)(col0 + br0) * K + (((tid & 3) ^ ((br0 >> 1) & 3)) << 3);
    const u16* bgp1 = Bt + (size_t)(col0 + br1) * K + (((tid & 3) ^ ((br1 >> 1) & 3)) << 3);
    u16* blds0 = Bs + w * 512;
    u16* blds1 = Bs + 2048 + w * 512;

    f32x4 acc[2][4];
#pragma unroll
    for (int m = 0; m < 2; ++m)
#pragma unroll
        for (int n = 0; n < 4; ++n) acc[m][n] = (f32x4){0.f, 0.f, 0.f, 0.f};

    int s = lane >> 4, r = lane & 15;
    int wr = (w >> 1) * 32, wc = (w & 1) * 64;

    for (int k0 = 0; k0 < K; k0 += 32) {
        gload16(agp + k0, alds);
        gload16(bgp0 + k0, blds0);
        gload16(bgp1 + k0, blds1);
        __syncthreads();
        bf16x8 a[2], bb[4];
#pragma unroll
        for (int m = 0; m < 2; ++m) {
            int row = wr + m * 16 + r;
            a[m] = *(const bf16x8*)&As[row * 32 + ((s ^ ((row >> 1) & 3)) << 3)];
        }
#pragma unroll
        for (int n = 0; n < 4; ++n) {
            int col = wc + n * 16 + r;
            bb[n] = *(const bf16x8*)&Bs[col * 32 + ((s ^ ((col >> 1) & 3)) << 3)];
        }
#pragma unroll
        for (int m = 0; m < 2; ++m)
#pragma unroll
            for (int n = 0; n < 4; ++n)
                acc[m][n] = __builtin_amdgcn_mfma_f32_16x16x32_bf16(a[m], bb[n], acc[m][n], 0, 0, 0);
        __syncthreads();
    }

#pragma unroll
    for (int m = 0; m < 2; ++m) {
#pragma unroll
        for (int n = 0; n < 4; ++n) {
            int gcol = col0 + wc + n * 16 + r;
#pragma unroll
            for (int j = 0; j < 4; ++j) {
                int grow = row0 + wr + m * 16 + s * 4 + j;
                if (grow < Mreal) {
                    u16 h = f2bf(acc[m][n][j]);
                    size_t idx;
                    if (gcol < 128) idx = (size_t)grow * 768 + gcol;
                    else {
                        int t2 = gcol - 128;
                        int gg = t2 / 640;
                        int ko = 128 + t2 - gg * 640;
                        idx = (size_t)(gg * 128 + grow) * 768 + ko;
                    }
                    C[idx] = h;
                }
            }
        }
    }
}

__global__ __launch_bounds__(256) void setup_gemm(
    const u16* __restrict__ xin, const u16* __restrict__ Wp,
    const float* __restrict__ biasl,
    u16* __restrict__ preC, u16* __restrict__ preB,
    const u16* __restrict__ WlinT, const u16* __restrict__ Wpostb,
    u16* __restrict__ BtK) {
    __shared__ u16 S[3][8192];
    int bx = blockIdx.x, tid = threadIdx.x;
    if (bx < 320) pre2_body(bx, tid, S, xin, Wp, biasl, preC, preB);
    else          wprod_body(bx - 320, tid, S[0], S[0] + 2048, WlinT, Wpostb, BtK);
}

// ---------------- pre2: 128-row tile, depth-2 counted-vmcnt pre GEMM ----------------

__global__ __launch_bounds__(256) void pre2(
    const u16* __restrict__ xin,        // [MROWS][128]
    const u16* __restrict__ Wp,         // WpreT layer base [256][128]
    const float* __restrict__ biasl,    // biaspre layer base [256]
    u16* __restrict__ preC, u16* __restrict__ preB) {
    __shared__ u16 S[3][8192];
    pre2_body(blockIdx.x, threadIdx.x, S, xin, Wp, biasl, preC, preB);
}

// ---------------- comb2: 128-row tile, depth-2 counted-vmcnt comb GEMM ----------------

template <bool OUT>
__global__ __launch_bounds__(256) void comb2(
    const u16* __restrict__ xin,        // [MROWS][128]
    const u16* __restrict__ aggb,       // [MROWS][640]
    const u16* __restrict__ BtK,        // [384][768], row = g*128 + outcol
    const float* __restrict__ bias,     // bcomb 128
    const float* __restrict__ amp, const float* __restrict__ att,
    u16* __restrict__ xout,             // [MROWS][128]  (!OUT)
    const float* __restrict__ Wout,     // [128]         (OUT)
    const float* __restrict__ bout,     // [1]           (OUT)
    float* __restrict__ y) {            // [NN]          (OUT)
    __shared__ u16 S[3][10240];         // 3 x 20 KB: A 128x32 @0, B 192x32 @4096 (u16)
    int g = blockIdx.x;
    int row = (g >> 4) * 8 + (g & 7);
    if (row >= 157) return;
    int row0 = row * 128;
    int cb = (g >> 3) & 1;              // 64-col half
    int tid = threadIdx.x;
    int w = tid >> 6, lane = tid & 63;
    int r = lane & 15, s4 = lane >> 4;
    int wr = (w >> 1) * 64, wc = (w & 1) * 32;

    int rtA0 = tid >> 2, qA = tid & 3;
    int rtA1 = rtA0 + 64;
    int koffA0 = (qA ^ ((rtA0 >> 1) & 3)) << 3;
    int koffA1 = (qA ^ ((rtA1 >> 1) & 3)) << 3;
    const u16* xA0 = xin + (size_t)(row0 + rtA0) * 128 + koffA0;
    const u16* xA1 = xin + (size_t)(row0 + rtA1) * 128 + koffA1;
    const u16* gA0 = aggb + (size_t)(row0 + rtA0) * 640 + koffA0 - 128;
    const u16* gA1 = aggb + (size_t)(row0 + rtA1) * 640 + koffA1 - 128;
    const u16* bB[3];
#pragma unroll
    for (int p = 2; p < 5; ++p) {
        int lid = tid + 256 * p;
        int rt = lid >> 2, q = lid & 3;
        int rb = rt - 128, gg = rb >> 6, jj = rb & 63;
        int koff = (q ^ ((rt >> 1) & 3)) << 3;
        bB[p - 2] = BtK + (size_t)(gg * 128 + cb * 64 + jj) * 768 + koff;
    }

    f32x4 acc[4][3][2];
#pragma unroll
    for (int m = 0; m < 4; ++m)
#pragma unroll
        for (int gg = 0; gg < 3; ++gg)
#pragma unroll
            for (int n = 0; n < 2; ++n) acc[m][gg][n] = (f32x4){0.f, 0.f, 0.f, 0.f};

    auto STAGE = [&](int t, int b) {
        const u16* a0 = (t < 4) ? (xA0 + t * 32) : (gA0 + t * 32);
        const u16* a1 = (t < 4) ? (xA1 + t * 32) : (gA1 + t * 32);
        gload16(a0, &S[b][(size_t)tid * 8]);
        gload16(a1, &S[b][(size_t)(tid + 256) * 8]);
#pragma unroll
        for (int p = 2; p < 5; ++p)
            gload16(bB[p - 2] + t * 32, &S[b][(size_t)(tid + 256 * p) * 8]);
    };

    STAGE(0, 0);
    STAGE(1, 1);
    asm volatile("s_waitcnt vmcnt(5)" ::: "memory");
    __builtin_amdgcn_s_barrier();
    asm volatile("" ::: "memory");

    int buf = 0;
    for (int t = 0; t < 24; ++t) {
        if (t + 2 < 24) STAGE(t + 2, (t + 2) % 3);
        const u16* Sb = S[buf];
        bf16x8 a[4];
#pragma unroll
        for (int m = 0; m < 4; ++m) {
            int rw = wr + m * 16 + r;
            a[m] = *(const bf16x8*)&Sb[rw * 32 + ((s4 ^ ((rw >> 1) & 3)) << 3)];
        }
#pragma unroll
        for (int gg = 0; gg < 3; ++gg) {
            if (gg > 0 && t < 4) continue;       // zero B-block for k<128
#pragma unroll
            for (int n = 0; n < 2; ++n) {
                int rb = gg * 64 + wc + n * 16 + r;
                bf16x8 b = *(const bf16x8*)&Sb[4096 + rb * 32 + ((s4 ^ ((rb >> 1) & 3)) << 3)];
#pragma unroll
                for (int m = 0; m < 4; ++m)
                    acc[m][gg][n] = __builtin_amdgcn_mfma_f32_16x16x32_bf16(a[m], b, acc[m][gg][n], 0, 0, 0);
            }
        }
        if (t < 23) {
            if (t + 2 < 24) asm volatile("s_waitcnt vmcnt(5)" ::: "memory");
            else            asm volatile("s_waitcnt vmcnt(0)" ::: "memory");
            __builtin_amdgcn_s_barrier();
            asm volatile("" ::: "memory");
        }
        buf = (buf == 2) ? 0 : buf + 1;
    }

    int gcb = cb * 64 + wc;
#pragma unroll
    for (int m = 0; m < 4; ++m)
#pragma unroll
        for (int j = 0; j < 4; ++j) {
            int grow = row0 + wr + m * 16 + s4 * 4 + j;
            if (grow >= NN) continue;
            float av = amp[grow], tv = att[grow];
            if (OUT) {
                float ps = 0.f;
#pragma unroll
                for (int n = 0; n < 2; ++n) {
                    int gcol = gcb + n * 16 + r;
                    float v = acc[m][0][n][j] + av * acc[m][1][n][j] + tv * acc[m][2][n][j] + bias[gcol];
                    v = fmaxf(v, 0.f);
                    ps = fmaf(v, Wout[gcol], ps);
                }
                ps += __shfl_xor(ps, 1, 16);
                ps += __shfl_xor(ps, 2, 16);
                ps += __shfl_xor(ps, 4, 16);
                ps += __shfl_xor(ps, 8, 16);
                if (r == 0) {
                    if (cb == 0 && wc == 0) ps += bout[0];
                    atomicAdd(&y[grow], ps);
                }
            } else {
#pragma unroll
                for (int n = 0; n < 2; ++n) {
                    int gcol = gcb + n * 16 + r;
                    float v = acc[m][0][n][j] + av * acc[m][1][n][j] + tv * acc[m][2][n][j] + bias[gcol];
                    v = fmaxf(v, 0.f);
                    xout[(size_t)grow * F + gcol] = f2bf(v);
                }
            }
        }
}

// ---------------- host ----------------

extern "C" void kernel_launch(void* const* d_in, const int* in_sizes, int n_in,
                              void* d_out, int out_size, void* d_ws, size_t ws_size,
                              hipStream_t stream) {
    const float* x_in   = (const float*)d_in[0];
    const int*   ei     = (const int*)d_in[1];
    const float* W_pre  = (const float*)d_in[2];
    const float* b_pre  = (const float*)d_in[3];
    const float* W_post = (const float*)d_in[4];
    const float* b_post = (const float*)d_in[5];
    const float* W_lin  = (const float*)d_in[6];
    const float* b_lin  = (const float*)d_in[7];
    const float* W_out  = (const float*)d_in[8];
    const float* b_out  = (const float*)d_in[9];

    const int* src = ei;
    const int* dst = ei + NE;

    double sl = 0.0;
    for (int i = 0; i < 33; ++i) sl += log((double)(i + 1));
    float avg_log = (float)(sl / 33.0);

    char* ws = (char*)d_ws;
    size_t p = 0;
    auto alloc = [&](size_t bytes) { void* r = ws + p; p += (bytes + 255) & ~(size_t)255; return r; };
    u16*   xbufA   = (u16*)alloc((size_t)MROWS * F * 2);
    u16*   xbufB   = (u16*)alloc((size_t)MROWS * F * 2);
    u16*   aggb    = (u16*)alloc((size_t)MROWS * 640 * 2);
    u16*   preC    = (u16*)alloc((size_t)MROWS * F * 2);
    u16*   preB    = (u16*)alloc((size_t)MROWS * F * 2);
    u16*   WpreT   = (u16*)alloc((size_t)3 * 256 * 128 * 2);
    u16*   Wpostb  = (u16*)alloc((size_t)3 * 2048 * 128 * 2);
    u16*   WlinT   = (u16*)alloc((size_t)3 * 128 * 128 * 2);
    u16*   BtK     = (u16*)alloc((size_t)3 * 384 * 768 * 2);
    float* biaspre = (float*)alloc((size_t)3 * 256 * 4);
    float* bcomb   = (float*)alloc((size_t)3 * 128 * 4);
    float* amp     = (float*)alloc((size_t)MPAD * 4);
    float* att     = (float*)alloc((size_t)MPAD * 4);
    int*   cnt     = (int*)alloc((size_t)NN * 4);
    int*   offs    = (int*)alloc((size_t)(NN + 1) * 4);
    int*   cur     = (int*)alloc((size_t)NN * 4);
    int*   csr     = (int*)alloc((size_t)NE * 4);
    int*   bsum    = (int*)alloc((size_t)SCAN_NB * 4);
    (void)ws_size;

    float* y = (float*)d_out;

    prep_all<<<(int)((P7 + 255) / 256), 256, 0, stream>>>(
        x_in, W_pre, W_lin, W_post, b_pre, b_post, b_lin,
        xbufA, WpreT, WlinT, Wpostb, biaspre, bcomb, cnt, cur, y);

    hist_kernel<<<(NE + 255) / 256, 256, 0, stream>>>(dst, cnt, NE);
    scan_p1<<<SCAN_NB, 256, 0, stream>>>(cnt, bsum);
    scan_p23<<<SCAN_NB, 256, 0, stream>>>(cnt, bsum, offs, amp, att, avg_log);
    scatter_kernel<<<(NE + 255) / 256, 256, 0, stream>>>(src, dst, offs, cur, csr, NE);

    // fused: BtK build (96 blocks) + layer-0 pre (320 blocks)
    setup_gemm<<<416, 256, 0, stream>>>(
        xbufA, WpreT, biaspre, preC, preB, WlinT, Wpostb, BtK);

    u16* xc = xbufA;
    u16* xn = xbufB;
    for (int l = 0; l < NLAYER; ++l) {
        agg_kernel<<<2048, 256, 0, stream>>>(preC, preB, offs, csr, aggb);
        if (l < NLAYER - 1) {
            comb2<false><<<320, 256, 0, stream>>>(
                xc, aggb, BtK + (size_t)l * 294912, bcomb + (size_t)l * 128,
                amp, att, xn, nullptr, nullptr, nullptr);
            pre2<<<320, 256, 0, stream>>>(
                xn, WpreT + (size_t)(l + 1) * 32768, biaspre + (size_t)(l + 1) * 256,
                preC, preB);
            u16* tmp = xc; xc = xn; xn = tmp;
        } else {
            comb2<true><<<320, 256, 0, stream>>>(
                xc, aggb, BtK + (size_t)l * 294912, bcomb + (size_t)l * 128,
                amp, att, nullptr, W_out, b_out, y);
        }
    }
}